// Round 5
// baseline (399.001 us; speedup 1.0000x reference)
//
#include <hip/hip_runtime.h>

#define NN 50000
#define EE 400000
#define FF 128
#define NRBF 20
#define MAXDEG 64
#define PI_OVER_CUT 0.6283185307179586f   // pi / 5.0

typedef _Float16 h8 __attribute__((ext_vector_type(8)));
typedef float    f4 __attribute__((ext_vector_type(4)));

union pk32 { unsigned int u; _Float16 h[2]; };

// ---------------------------------------------------------------------------
__global__ __launch_bounds__(256) void k_zero(int* __restrict__ counts) {
    int i = blockIdx.x * 256 + threadIdx.x;
    if (i < NN) counts[i] = 0;
}

__global__ __launch_bounds__(256) void k_bucket(const int* __restrict__ dst,
                                                int* __restrict__ counts,
                                                int* __restrict__ slots) {
    int e = blockIdx.x * 256 + threadIdx.x;
    if (e < EE) {
        int n = dst[e];
        int slot = atomicAdd(&counts[n], 1);
        if (slot < MAXDEG) slots[n * MAXDEG + slot] = e;
    }
}

// Convert all GEMM weights to f16 once (L2-resident afterwards).
__global__ __launch_bounds__(256) void k_wconv(
    const float* __restrict__ Wu, const float* __restrict__ Wv,
    const float* __restrict__ Wu1, const float* __restrict__ Wu2,
    const float* __restrict__ Wp1, const float* __restrict__ Wp2,
    const float* __restrict__ Ww, const float* __restrict__ bw,
    _Float16* __restrict__ Wuh, _Float16* __restrict__ Wvh,
    _Float16* __restrict__ Wu1h, _Float16* __restrict__ Wu2h,
    _Float16* __restrict__ Wp1h, _Float16* __restrict__ Wp2h,
    _Float16* __restrict__ Wwh32)
{
    int i = blockIdx.x * 256 + threadIdx.x;
    if (i < 16384) { Wuh[i] = (_Float16)Wu[i]; Wvh[i] = (_Float16)Wv[i];
                     Wp1h[i] = (_Float16)Wp1[i]; }
    if (i < 32768) { Wu1h[i] = (_Float16)Wu1[i]; }
    if (i < 49152) { Wu2h[i] = (_Float16)Wu2[i]; Wp2h[i] = (_Float16)Wp2[i]; }
    if (i < 8192) {
        int col = i >> 5, k = i & 31;
        int sr = col < 128 ? col : col + 128;
        _Float16 v = (_Float16)0.f;
        if (k < 20)       v = (_Float16)Ww[sr * NRBF + k];
        else if (k == 20) v = (_Float16)bw[sr];
        Wwh32[i] = v;
    }
}

// ---------------------------------------------------------------------------
// K1 (MFMA): s0 = emb[z]; h1 = silu(Wp1 s + bp1); phi = Wp2 h1 + bp2.
__global__ __launch_bounds__(256) void k_node_phi_mfma(
    const float* __restrict__ emb, const int* __restrict__ z,
    const _Float16* __restrict__ Wp1h, const float* __restrict__ bp1,
    const _Float16* __restrict__ Wp2h, const float* __restrict__ bp2,
    unsigned int* __restrict__ phi_pk, float* __restrict__ s_io)
{
    __shared__ _Float16 Ss[32 * 128];
    __shared__ _Float16 H1s[32 * 128];

    const int t    = threadIdx.x;
    const int lane = t & 63;
    const int w    = t >> 6;
    const int lr   = lane & 15;
    const int lq   = lane >> 4;
    const int n0   = blockIdx.x * 32;
    const f4 z4 = {0.f, 0.f, 0.f, 0.f};

    for (int i = t; i < 512; i += 256) {             // 32 rows x 16 granules
        int n = i >> 4, gr = i & 15;
        int nn = n0 + n; if (nn > NN - 1) nn = NN - 1;
        const float* sp = &emb[(size_t)z[nn] * FF + gr * 8];
        float4 aa = *(const float4*)sp;
        float4 bb = *(const float4*)(sp + 4);
        h8 hv;
        hv[0] = (_Float16)aa.x; hv[1] = (_Float16)aa.y;
        hv[2] = (_Float16)aa.z; hv[3] = (_Float16)aa.w;
        hv[4] = (_Float16)bb.x; hv[5] = (_Float16)bb.y;
        hv[6] = (_Float16)bb.z; hv[7] = (_Float16)bb.w;
        *(h8*)&Ss[(n * 16 + (gr ^ (n & 15))) * 8] = hv;
        float* op = &s_io[(size_t)nn * FF + gr * 8];
        *(float4*)op       = aa;
        *(float4*)(op + 4) = bb;
    }
    __syncthreads();

    f4 acc1[2][2];
    #pragma unroll
    for (int a = 0; a < 2; ++a)
        #pragma unroll
        for (int m = 0; m < 2; ++m) acc1[a][m] = z4;
    {
        const _Float16* bb = Wp1h + (size_t)lr * 128 + lq * 8;
        #pragma unroll
        for (int g2 = 0; g2 < 2; ++g2) {
            h8 bf[4];
            #pragma unroll
            for (int ks = 0; ks < 4; ++ks)
                bf[ks] = *(const h8*)(bb + ((2 * w + g2) * 16) * 128 + ks * 32);
            #pragma unroll
            for (int mt = 0; mt < 2; ++mt) {
                const int r = mt * 16 + lr;
                #pragma unroll
                for (int ks = 0; ks < 4; ++ks) {
                    h8 af = *(const h8*)&Ss[(r * 16 + ((ks * 4 + lq) ^ (r & 15))) * 8];
                    acc1[g2][mt] = __builtin_amdgcn_mfma_f32_16x16x32_f16(
                        af, bf[ks], acc1[g2][mt], 0, 0, 0);
                }
            }
        }
    }
    #pragma unroll
    for (int g2 = 0; g2 < 2; ++g2) {
        const int g = (2 * w + g2) * 16 + lr;
        const float b1 = bp1[g];
        #pragma unroll
        for (int mt = 0; mt < 2; ++mt)
            #pragma unroll
            for (int r = 0; r < 4; ++r) {
                float x = acc1[g2][mt][r] + b1;
                float y = x / (1.f + __expf(-x));
                int n = mt * 16 + lq * 4 + r;
                H1s[(n * 16 + ((g >> 3) ^ (n & 15))) * 8 + (g & 7)] = (_Float16)y;
            }
    }
    __syncthreads();

    f4 accS[2][2], accV[2][2];
    #pragma unroll
    for (int a = 0; a < 2; ++a)
        #pragma unroll
        for (int m = 0; m < 2; ++m) { accS[a][m] = z4; accV[a][m] = z4; }
    {
        const _Float16* bbs = Wp2h + (size_t)lr * 128 + lq * 8;
        const _Float16* bbv = Wp2h + (size_t)(256 + lr) * 128 + lq * 8;
        #pragma unroll
        for (int g2 = 0; g2 < 2; ++g2) {
            h8 bfs[4], bfv[4];
            #pragma unroll
            for (int ks = 0; ks < 4; ++ks) {
                bfs[ks] = *(const h8*)(bbs + ((2 * w + g2) * 16) * 128 + ks * 32);
                bfv[ks] = *(const h8*)(bbv + ((2 * w + g2) * 16) * 128 + ks * 32);
            }
            #pragma unroll
            for (int mt = 0; mt < 2; ++mt) {
                const int r = mt * 16 + lr;
                #pragma unroll
                for (int ks = 0; ks < 4; ++ks) {
                    h8 af = *(const h8*)&H1s[(r * 16 + ((ks * 4 + lq) ^ (r & 15))) * 8];
                    accS[g2][mt] = __builtin_amdgcn_mfma_f32_16x16x32_f16(
                        af, bfs[ks], accS[g2][mt], 0, 0, 0);
                    accV[g2][mt] = __builtin_amdgcn_mfma_f32_16x16x32_f16(
                        af, bfv[ks], accV[g2][mt], 0, 0, 0);
                }
            }
        }
    }
    #pragma unroll
    for (int g2 = 0; g2 < 2; ++g2) {
        const int g = (2 * w + g2) * 16 + lr;
        const float bsa = bp2[g], bva = bp2[256 + g];
        #pragma unroll
        for (int mt = 0; mt < 2; ++mt)
            #pragma unroll
            for (int r = 0; r < 4; ++r) {
                int n = mt * 16 + lq * 4 + r;
                int nn = n0 + n;
                if (nn < NN) {
                    pk32 pk;
                    pk.h[0] = (_Float16)(accS[g2][mt][r] + bsa);
                    pk.h[1] = (_Float16)(accV[g2][mt][r] + bva);
                    phi_pk[(size_t)nn * FF + g] = pk.u;
                }
            }
    }
}

// ---------------------------------------------------------------------------
// K2 (MFMA Wf, persistent): grid-stride over nodes. B-fragments loaded once
// per block; next node's header chain (counts/slots/src/pos) prefetched into
// registers while the current node computes; phi gathers issued 16-wide.
__global__ __launch_bounds__(128) void k_edge_mfma(
    const float* __restrict__ pos,
    const _Float16* __restrict__ Wwh32,
    const int* __restrict__ src,
    const int* __restrict__ counts, const int* __restrict__ slots,
    const unsigned int* __restrict__ phi_pk,
    float* __restrict__ s_io,
    _Float16* __restrict__ xg)
{
    __shared__ _Float16 A[16 * 32];          // swizzled rbf A-tile (1 KB)
    __shared__ float dirs[16][4];            // ux, uy, uz, asfloat(sI)
    __shared__ float dls[16];                // distance per edge
    __shared__ unsigned int wf[16 * 130];    // interleaved {s,v} f16 Wf (8.3 KB)

    const int t    = threadIdx.x;
    const int lane = t & 63;
    const int w    = t >> 6;     // wave 0 = s-half, wave 1 = v-half
    const int lr   = lane & 15;
    const int lq   = lane >> 4;
    const f4 z4 = {0.f, 0.f, 0.f, 0.f};

    // B-fragments: loaded once per persistent block (L2-hot).
    h8 bf[8];
    #pragma unroll
    for (int j = 0; j < 8; ++j)
        bf[j] = *(const h8*)&Wwh32[(size_t)((w * 8 + j) * 16 + lr) * 32 + lq * 8];

    const int G = gridDim.x;

    // ---- prologue prefetch (node blockIdx.x) ----
    int   deg_pf = 0;
    float dpx = 0.f, dpy = 0.f, dpz = 0.f;
    int   sI_pf = 0;
    float spx = 0.f, spy = 0.f, spz = 0.f;
    {
        int n1 = blockIdx.x;
        if (n1 < NN) {
            deg_pf = counts[n1];
            dpx = pos[3 * n1]; dpy = pos[3 * n1 + 1]; dpz = pos[3 * n1 + 2];
            if (t < 16) {
                int e = slots[n1 * MAXDEG + t];
                if ((unsigned)e >= EE) e = 0;    // stale slot -> safe clamp
                sI_pf = src[e];
                spx = pos[3 * sI_pf];
                spy = pos[3 * sI_pf + 1];
                spz = pos[3 * sI_pf + 2];
            }
        }
    }

    for (int n = blockIdx.x; n < NN; n += G) {
        int deg = deg_pf; deg = deg > MAXDEG ? MAXDEG : deg;
        const float px = dpx, py = dpy, pz = dpz;
        const int   sIc = sI_pf;
        const float sxc = spx, syc = spy, szc = spz;

        float acc_s = 0.f, av0 = 0.f, av1 = 0.f, av2 = 0.f;
        const size_t gi = (size_t)n * FF + t;

        __syncthreads();                     // prev iteration's LDS reads done
        // ---- phase 1 (first tile): geometry from prefetched registers ----
        const int degT0 = deg < 16 ? deg : 16;
        if (t < degT0) {
            float rx = px - sxc, ry = py - syc, rz = pz - szc;
            float d = sqrtf(rx * rx + ry * ry + rz * rz);
            d = fmaxf(d, 1e-9f);
            float di = 1.f / d;
            dirs[t][0] = rx * di;
            dirs[t][1] = ry * di;
            dirs[t][2] = rz * di;
            dirs[t][3] = __int_as_float(sIc);
            dls[t] = d;
        }
        // s_io old value: issue early, consumed at the end of this node.
        float s_old = s_io[gi];
        __syncthreads();

        // ---- issue prefetch for node n+G (waited next iteration) ----
        {
            int n2 = n + G;
            deg_pf = 0;
            if (n2 < NN) {
                deg_pf = counts[n2];
                dpx = pos[3 * n2]; dpy = pos[3 * n2 + 1]; dpz = pos[3 * n2 + 2];
                if (t < 16) {
                    int e = slots[n2 * MAXDEG + t];
                    if ((unsigned)e >= EE) e = 0;
                    sI_pf = src[e];
                    spx = pos[3 * sI_pf];
                    spy = pos[3 * sI_pf + 1];
                    spz = pos[3 * sI_pf + 2];
                }
            }
        }

        // ---- phase 2: rbf -> A-tile (edge m = t&15, k-slot kk = t>>4) ----
        {
            const int m = t & 15, kk = t >> 4;
            float d  = dls[m];
            float di = 1.f / d;
            float v0 = __sinf((float)(kk + 1) * PI_OVER_CUT * d) * di;
            float v1 = __sinf((float)(kk + 9) * PI_OVER_CUT * d) * di;
            float v2;
            if (kk < 4)       v2 = __sinf((float)(kk + 17) * PI_OVER_CUT * d) * di;
            else if (kk == 4) v2 = 1.0f;     // k=20: bias element
            else              v2 = 0.f;
            #define STO(K, V) A[m * 32 + (((K) >> 3) ^ (m & 3)) * 8 + ((K) & 7)] = (_Float16)(V)
            STO(kk,      v0);
            STO(kk + 8,  v1);
            STO(kk + 16, v2);
            STO(kk + 24, 0.f);
            #undef STO
        }
        __syncthreads();
        // ---- MFMA: Wf tile ----
        {
            h8 af = *(const h8*)&A[(lr * 4 + (lq ^ (lr & 3))) * 8];
            #pragma unroll
            for (int j = 0; j < 8; ++j) {
                f4 dd = __builtin_amdgcn_mfma_f32_16x16x32_f16(af, bf[j], z4, 0, 0, 0);
                #pragma unroll
                for (int r = 0; r < 4; ++r) {
                    int m = lq * 4 + r;
                    ((_Float16*)&wf[m * 130 + j * 16 + lr])[w] = (_Float16)dd[r];
                }
            }
        }
        __syncthreads();
        // ---- accumulate: 16-wide batched phi gathers, then FMA pass ----
        {
            unsigned int phr[16];
            #pragma unroll
            for (int m = 0; m < 16; ++m) {
                int sIm = __float_as_int(dirs[m][3]);
                unsigned int v = 0u;
                if (m < degT0) v = phi_pk[(size_t)sIm * FF + t];
                phr[m] = v;
            }
            #pragma unroll
            for (int m = 0; m < 16; ++m) {
                if (m < degT0) {
                    pk32 ph, wfu;
                    ph.u  = phr[m];
                    wfu.u = wf[m * 130 + t];
                    float ps = (float)ph.h[0] * (float)wfu.h[0];
                    float pv = (float)ph.h[1] * (float)wfu.h[1];
                    acc_s += ps;
                    av0 = fmaf(pv, dirs[m][0], av0);
                    av1 = fmaf(pv, dirs[m][1], av1);
                    av2 = fmaf(pv, dirs[m][2], av2);
                }
            }
        }

        // ---- rare extra tiles (deg > 16): in-place path ----
        for (int t0 = 16; t0 < deg; t0 += 16) {
            const int degT = (deg - t0) < 16 ? (deg - t0) : 16;
            __syncthreads();
            if (t < degT) {
                int e  = slots[n * MAXDEG + t0 + t];
                int sI = src[e];
                float rx = px - pos[3 * sI];
                float ry = py - pos[3 * sI + 1];
                float rz = pz - pos[3 * sI + 2];
                float d = sqrtf(rx * rx + ry * ry + rz * rz);
                d = fmaxf(d, 1e-9f);
                float di = 1.f / d;
                dirs[t][0] = rx * di;
                dirs[t][1] = ry * di;
                dirs[t][2] = rz * di;
                dirs[t][3] = __int_as_float(sI);
                dls[t] = d;
            }
            __syncthreads();
            {
                const int m = t & 15, kk = t >> 4;
                float d  = dls[m];
                float di = 1.f / d;
                float v0 = __sinf((float)(kk + 1) * PI_OVER_CUT * d) * di;
                float v1 = __sinf((float)(kk + 9) * PI_OVER_CUT * d) * di;
                float v2;
                if (kk < 4)       v2 = __sinf((float)(kk + 17) * PI_OVER_CUT * d) * di;
                else if (kk == 4) v2 = 1.0f;
                else              v2 = 0.f;
                #define STO(K, V) A[m * 32 + (((K) >> 3) ^ (m & 3)) * 8 + ((K) & 7)] = (_Float16)(V)
                STO(kk,      v0);
                STO(kk + 8,  v1);
                STO(kk + 16, v2);
                STO(kk + 24, 0.f);
                #undef STO
            }
            __syncthreads();
            {
                h8 af = *(const h8*)&A[(lr * 4 + (lq ^ (lr & 3))) * 8];
                #pragma unroll
                for (int j = 0; j < 8; ++j) {
                    f4 dd = __builtin_amdgcn_mfma_f32_16x16x32_f16(af, bf[j], z4, 0, 0, 0);
                    #pragma unroll
                    for (int r = 0; r < 4; ++r) {
                        int m = lq * 4 + r;
                        ((_Float16*)&wf[m * 130 + j * 16 + lr])[w] = (_Float16)dd[r];
                    }
                }
            }
            __syncthreads();
            for (int m = 0; m < degT; ++m) {
                float4 dir = *(const float4*)&dirs[m][0];
                int sI = __builtin_amdgcn_readfirstlane(__float_as_int(dir.w));
                pk32 ph, wfu;
                ph.u  = phi_pk[(size_t)sI * FF + t];
                wfu.u = wf[m * 130 + t];
                float ps = (float)ph.h[0] * (float)wfu.h[0];
                float pv = (float)ph.h[1] * (float)wfu.h[1];
                acc_s += ps;
                av0 = fmaf(pv, dir.x, av0);
                av1 = fmaf(pv, dir.y, av1);
                av2 = fmaf(pv, dir.z, av2);
            }
        }

        // ---- outputs for node n ----
        s_io[gi] = s_old + acc_s;
        xg[((size_t)n * 3 + 0) * FF + t] = (_Float16)av0;
        xg[((size_t)n * 3 + 1) * FF + t] = (_Float16)av1;
        xg[((size_t)n * 3 + 2) * FF + t] = (_Float16)av2;
    }
}

// ---------------------------------------------------------------------------
// K3: update block on f16 MFMA. Residuals (s, v) come from the staged f16
// LDS tiles (Hs, Xs); v_io is write-only.
__global__ __launch_bounds__(256) void k_update_mfma(
    const _Float16* __restrict__ xg,
    const _Float16* __restrict__ Wuh, const _Float16* __restrict__ Wvh,
    const _Float16* __restrict__ Wu1h, const _Float16* __restrict__ Wu2h,
    const float* __restrict__ bu, const float* __restrict__ bv,
    const float* __restrict__ bu1, const float* __restrict__ bu2,
    float* __restrict__ s_io, float* __restrict__ v_io)
{
    __shared__ _Float16 Xs[96 * 128];    // A for GEMM1: row = c*32+n, k = f
    __shared__ _Float16 Hs[32 * 256];    // A for GEMM2: [s | Vn]
    __shared__ _Float16 H1s[32 * 128];   // A for GEMM3

    const int t    = threadIdx.x;
    const int lane = t & 63;
    const int w    = t >> 6;     // wave 0..3
    const int lr   = lane & 15;  // A-row / B-col within tile
    const int lq   = lane >> 4;  // k-chunk selector
    const int n0   = blockIdx.x * 32;
    const f4 z4 = {0.f, 0.f, 0.f, 0.f};

    for (int i = t; i < 1536; i += 256) {            // 96 rows x 16 granules
        int row = i >> 4, gr = i & 15;
        int n = row & 31, c = row >> 5;
        int nn = n0 + n; if (nn > NN - 1) nn = NN - 1;
        uint4 d = *(const uint4*)&xg[((size_t)nn * 3 + c) * FF + gr * 8];
        *(uint4*)&Xs[(row * 16 + (gr ^ (row & 15))) * 8] = d;
    }
    for (int i = t; i < 512; i += 256) {             // 32 rows x 16 granules
        int n = i >> 4, gr = i & 15;
        int nn = n0 + n; if (nn > NN - 1) nn = NN - 1;
        const float* sp = &s_io[(size_t)nn * FF + gr * 8];
        float4 aa = *(const float4*)sp;
        float4 bb = *(const float4*)(sp + 4);
        h8 hv;
        hv[0] = (_Float16)aa.x; hv[1] = (_Float16)aa.y;
        hv[2] = (_Float16)aa.z; hv[3] = (_Float16)aa.w;
        hv[4] = (_Float16)bb.x; hv[5] = (_Float16)bb.y;
        hv[6] = (_Float16)bb.z; hv[7] = (_Float16)bb.w;
        *(h8*)&Hs[(n * 32 + (gr ^ (n & 15))) * 8] = hv;
    }
    __syncthreads();

    f4 accU[2][6], accV[2][6];   // [g-subtile][mt = c*2+p]
    #pragma unroll
    for (int a = 0; a < 2; ++a)
        #pragma unroll
        for (int m = 0; m < 6; ++m) { accU[a][m] = z4; accV[a][m] = z4; }

    {   // U pass
        const _Float16* bb = Wuh + (size_t)lr * 128 + lq * 8;
        h8 bfr[2][4];
        #pragma unroll
        for (int g2 = 0; g2 < 2; ++g2)
            #pragma unroll
            for (int ks = 0; ks < 4; ++ks)
                bfr[g2][ks] = *(const h8*)(bb + ((2 * w + g2) * 16) * 128 + ks * 32);
        #pragma unroll
        for (int mt = 0; mt < 6; ++mt) {
            const int r = mt * 16 + lr;
            h8 af[4];
            #pragma unroll
            for (int ks = 0; ks < 4; ++ks)
                af[ks] = *(const h8*)&Xs[(r * 16 + ((ks * 4 + lq) ^ (r & 15))) * 8];
            #pragma unroll
            for (int g2 = 0; g2 < 2; ++g2)
                #pragma unroll
                for (int ks = 0; ks < 4; ++ks)
                    accU[g2][mt] = __builtin_amdgcn_mfma_f32_16x16x32_f16(
                        af[ks], bfr[g2][ks], accU[g2][mt], 0, 0, 0);
        }
    }
    {   // V pass
        const _Float16* bb = Wvh + (size_t)lr * 128 + lq * 8;
        h8 bfr[2][4];
        #pragma unroll
        for (int g2 = 0; g2 < 2; ++g2)
            #pragma unroll
            for (int ks = 0; ks < 4; ++ks)
                bfr[g2][ks] = *(const h8*)(bb + ((2 * w + g2) * 16) * 128 + ks * 32);
        #pragma unroll
        for (int mt = 0; mt < 6; ++mt) {
            const int r = mt * 16 + lr;
            h8 af[4];
            #pragma unroll
            for (int ks = 0; ks < 4; ++ks)
                af[ks] = *(const h8*)&Xs[(r * 16 + ((ks * 4 + lq) ^ (r & 15))) * 8];
            #pragma unroll
            for (int g2 = 0; g2 < 2; ++g2)
                #pragma unroll
                for (int ks = 0; ks < 4; ++ks)
                    accV[g2][mt] = __builtin_amdgcn_mfma_f32_16x16x32_f16(
                        af[ks], bfr[g2][ks], accV[g2][mt], 0, 0, 0);
        }
    }

    float uvr[2][2][4];
    #pragma unroll
    for (int g2 = 0; g2 < 2; ++g2) {
        const int g = (2 * w + g2) * 16 + lr;
        const float bU = bu[g], bV = bv[g];
        #pragma unroll
        for (int p = 0; p < 2; ++p) {
            #pragma unroll
            for (int r = 0; r < 4; ++r) {
                float Ux = accU[g2][0 + p][r] + bU;
                float Uy = accU[g2][2 + p][r] + bU;
                float Uz = accU[g2][4 + p][r] + bU;
                float Vx = accV[g2][0 + p][r] + bV;
                float Vy = accV[g2][2 + p][r] + bV;
                float Vz = accV[g2][4 + p][r] + bV;
                accU[g2][0 + p][r] = Ux;
                accU[g2][2 + p][r] = Uy;
                accU[g2][4 + p][r] = Uz;
                uvr[g2][p][r] = Ux * Vx + Uy * Vy + Uz * Vz;
                float vn = sqrtf(Vx * Vx + Vy * Vy + Vz * Vz);
                int n = p * 16 + lq * 4 + r;
                int gr = 16 + (g >> 3);
                Hs[(n * 32 + (gr ^ (n & 15))) * 8 + (g & 7)] = (_Float16)vn;
            }
        }
    }
    __syncthreads();

    f4 acc2[2][2];
    #pragma unroll
    for (int a = 0; a < 2; ++a)
        #pragma unroll
        for (int m = 0; m < 2; ++m) acc2[a][m] = z4;
    {
        const _Float16* bb = Wu1h + (size_t)lr * 256 + lq * 8;
        #pragma unroll
        for (int g2 = 0; g2 < 2; ++g2) {
            h8 bfr[8];
            #pragma unroll
            for (int ks = 0; ks < 8; ++ks)
                bfr[ks] = *(const h8*)(bb + ((2 * w + g2) * 16) * 256 + ks * 32);
            #pragma unroll
            for (int mt = 0; mt < 2; ++mt) {
                const int r = mt * 16 + lr;
                #pragma unroll
                for (int ks = 0; ks < 8; ++ks) {
                    h8 af = *(const h8*)&Hs[(r * 32 + ((ks * 4 + lq) ^ (r & 15))) * 8];
                    acc2[g2][mt] = __builtin_amdgcn_mfma_f32_16x16x32_f16(
                        af, bfr[ks], acc2[g2][mt], 0, 0, 0);
                }
            }
        }
    }
    #pragma unroll
    for (int g2 = 0; g2 < 2; ++g2) {
        const int g = (2 * w + g2) * 16 + lr;
        const float b1 = bu1[g];
        #pragma unroll
        for (int mt = 0; mt < 2; ++mt)
            #pragma unroll
            for (int r = 0; r < 4; ++r) {
                float x = acc2[g2][mt][r] + b1;
                float y = x / (1.f + __expf(-x));
                int n = mt * 16 + lq * 4 + r;
                int gr = g >> 3;
                H1s[(n * 16 + (gr ^ (n & 15))) * 8 + (g & 7)] = (_Float16)y;
            }
    }
    __syncthreads();

    f4 acc3[3][2][2];
    #pragma unroll
    for (int a = 0; a < 3; ++a)
        #pragma unroll
        for (int b = 0; b < 2; ++b)
            #pragma unroll
            for (int m = 0; m < 2; ++m) acc3[a][b][m] = z4;
    {
        const _Float16* bb = Wu2h + (size_t)lr * 128 + lq * 8;
        #pragma unroll
        for (int ai = 0; ai < 3; ++ai)
            #pragma unroll
            for (int g2 = 0; g2 < 2; ++g2) {
                const int jt = ai * 8 + 2 * w + g2;
                h8 bfr[4];
                #pragma unroll
                for (int ks = 0; ks < 4; ++ks)
                    bfr[ks] = *(const h8*)(bb + (size_t)(jt * 16) * 128 + ks * 32);
                #pragma unroll
                for (int mt = 0; mt < 2; ++mt) {
                    const int r = mt * 16 + lr;
                    #pragma unroll
                    for (int ks = 0; ks < 4; ++ks) {
                        h8 af = *(const h8*)&H1s[(r * 16 + ((ks * 4 + lq) ^ (r & 15))) * 8];
                        acc3[ai][g2][mt] = __builtin_amdgcn_mfma_f32_16x16x32_f16(
                            af, bfr[ks], acc3[ai][g2][mt], 0, 0, 0);
                    }
                }
            }
    }

    // ---- final epilogue: residuals from staged f16 LDS tiles ----
    #pragma unroll
    for (int g2 = 0; g2 < 2; ++g2) {
        const int g = (2 * w + g2) * 16 + lr;
        const float b1 = bu2[g], b2 = bu2[128 + g], b3 = bu2[256 + g];
        #pragma unroll
        for (int p = 0; p < 2; ++p)
            #pragma unroll
            for (int r = 0; r < 4; ++r) {
                int n = p * 16 + lq * 4 + r;
                int nn = n0 + n;
                if (nn < NN) {
                    float a1 = acc3[0][g2][p][r] + b1;
                    float a2 = acc3[1][g2][p][r] + b2;
                    float a3 = acc3[2][g2][p][r] + b3;
                    size_t gi = (size_t)nn * FF + g;
                    float s1 = (float)Hs[(n * 32 + ((g >> 3) ^ (n & 15))) * 8 + (g & 7)];
                    s_io[gi] = s1 + a2 + uvr[g2][p][r] * a3;
                    float vx = (float)Xs[((0 * 32 + n) * 16 + ((g >> 3) ^ (n & 15))) * 8 + (g & 7)];
                    float vy = (float)Xs[((1 * 32 + n) * 16 + ((g >> 3) ^ (n & 15))) * 8 + (g & 7)];
                    float vz = (float)Xs[((2 * 32 + n) * 16 + ((g >> 3) ^ (n & 15))) * 8 + (g & 7)];
                    v_io[gi * 3 + 0] = vx + accU[g2][0 + p][r] * a1;
                    v_io[gi * 3 + 1] = vy + accU[g2][2 + p][r] * a1;
                    v_io[gi * 3 + 2] = vz + accU[g2][4 + p][r] * a1;
                }
            }
    }
}

// ---------------------------------------------------------------------------
extern "C" void kernel_launch(void* const* d_in, const int* in_sizes, int n_in,
                              void* d_out, int out_size, void* d_ws, size_t ws_size,
                              hipStream_t stream)
{
    const float* pos = (const float*)d_in[0];
    const float* emb = (const float*)d_in[1];
    const float* Wp1 = (const float*)d_in[2];
    const float* bp1 = (const float*)d_in[3];
    const float* Wp2 = (const float*)d_in[4];
    const float* bp2 = (const float*)d_in[5];
    const float* Ww  = (const float*)d_in[6];
    const float* bw  = (const float*)d_in[7];
    const float* Wu  = (const float*)d_in[8];
    const float* bu  = (const float*)d_in[9];
    const float* Wv  = (const float*)d_in[10];
    const float* bv  = (const float*)d_in[11];
    const float* Wu1 = (const float*)d_in[12];
    const float* bu1 = (const float*)d_in[13];
    const float* Wu2 = (const float*)d_in[14];
    const float* bu2 = (const float*)d_in[15];
    const int* z   = (const int*)d_in[16];
    const int* src = (const int*)d_in[17];
    const int* dst = (const int*)d_in[18];

    float* s_io = (float*)d_out;
    float* v_io = (float*)d_out + (size_t)NN * FF;

    char* ws = (char*)d_ws;
    unsigned int* phi_pk = (unsigned int*)ws;            // NN*FF uints
    _Float16* xg    = (_Float16*)(phi_pk + (size_t)NN * FF);  // NN*3*FF
    _Float16* Wuh   = xg + (size_t)NN * 3 * FF;
    _Float16* Wvh   = Wuh  + 128 * 128;
    _Float16* Wu1h  = Wvh  + 128 * 128;
    _Float16* Wu2h  = Wu1h + 128 * 256;
    _Float16* Wp1h  = Wu2h + 384 * 128;
    _Float16* Wp2h  = Wp1h + 128 * 128;
    _Float16* Wwh32 = Wp2h + 384 * 128;                  // 256*32
    int* counts = (int*)(Wwh32 + 256 * 32);
    int* slots  = counts + NN;

    k_zero  <<<(NN + 255) / 256, 256, 0, stream>>>(counts);
    k_bucket<<<(EE + 255) / 256, 256, 0, stream>>>(dst, counts, slots);
    k_wconv <<<192, 256, 0, stream>>>(Wu, Wv, Wu1, Wu2, Wp1, Wp2, Ww, bw,
                                      Wuh, Wvh, Wu1h, Wu2h, Wp1h, Wp2h, Wwh32);
    k_node_phi_mfma<<<(NN + 31) / 32, 256, 0, stream>>>(emb, z, Wp1h, bp1,
                                                        Wp2h, bp2,
                                                        phi_pk, s_io);
    k_edge_mfma<<<3072, 128, 0, stream>>>(pos, Wwh32, src, counts, slots,
                                          phi_pk, s_io, xg);
    k_update_mfma<<<(NN + 31) / 32, 256, 0, stream>>>(xg, Wuh, Wvh, Wu1h, Wu2h,
                                                      bu, bv, bu1, bu2, s_io, v_io);
}

// Round 6
// 388.526 us; speedup vs baseline: 1.0270x; 1.0270x over previous
//
#include <hip/hip_runtime.h>

#define NN 50000
#define EE 400000
#define FF 128
#define NRBF 20
#define MAXDEG 64
#define PI_OVER_CUT 0.6283185307179586f   // pi / 5.0

typedef _Float16 h8 __attribute__((ext_vector_type(8)));
typedef float    f4 __attribute__((ext_vector_type(4)));

union pk32 { unsigned int u; _Float16 h[2]; };

// ---------------------------------------------------------------------------
__global__ __launch_bounds__(256) void k_bucket(const int* __restrict__ dst,
                                                int* __restrict__ counts,
                                                int* __restrict__ slots) {
    int e = blockIdx.x * 256 + threadIdx.x;
    if (e < EE) {
        int n = dst[e];
        int slot = atomicAdd(&counts[n], 1);
        if (slot < MAXDEG) slots[n * MAXDEG + slot] = e;
    }
}

// Convert all GEMM weights to f16 once; also zeroes counts (merged k_zero).
__global__ __launch_bounds__(256) void k_wconv(
    const float* __restrict__ Wu, const float* __restrict__ Wv,
    const float* __restrict__ Wu1, const float* __restrict__ Wu2,
    const float* __restrict__ Wp1, const float* __restrict__ Wp2,
    const float* __restrict__ Ww, const float* __restrict__ bw,
    _Float16* __restrict__ Wuh, _Float16* __restrict__ Wvh,
    _Float16* __restrict__ Wu1h, _Float16* __restrict__ Wu2h,
    _Float16* __restrict__ Wp1h, _Float16* __restrict__ Wp2h,
    _Float16* __restrict__ Wwh32, int* __restrict__ counts)
{
    int i = blockIdx.x * 256 + threadIdx.x;
    if (i < NN) counts[i] = 0;
    if (i < 16384) { Wuh[i] = (_Float16)Wu[i]; Wvh[i] = (_Float16)Wv[i];
                     Wp1h[i] = (_Float16)Wp1[i]; }
    if (i < 32768) { Wu1h[i] = (_Float16)Wu1[i]; }
    if (i < 49152) { Wu2h[i] = (_Float16)Wu2[i]; Wp2h[i] = (_Float16)Wp2[i]; }
    if (i < 8192) {
        int col = i >> 5, k = i & 31;
        int sr = col < 128 ? col : col + 128;
        _Float16 v = (_Float16)0.f;
        if (k < 20)       v = (_Float16)Ww[sr * NRBF + k];
        else if (k == 20) v = (_Float16)bw[sr];
        Wwh32[i] = v;
    }
}

// ---------------------------------------------------------------------------
// K1 (MFMA): s0 = emb[z]; h1 = silu(Wp1 s + bp1); phi = Wp2 h1 + bp2.
// s0 carried forward as f16 (s_h).
__global__ __launch_bounds__(256) void k_node_phi_mfma(
    const float* __restrict__ emb, const int* __restrict__ z,
    const _Float16* __restrict__ Wp1h, const float* __restrict__ bp1,
    const _Float16* __restrict__ Wp2h, const float* __restrict__ bp2,
    unsigned int* __restrict__ phi_pk, _Float16* __restrict__ s_h)
{
    __shared__ _Float16 Ss[32 * 128];
    __shared__ _Float16 H1s[32 * 128];

    const int t    = threadIdx.x;
    const int lane = t & 63;
    const int w    = t >> 6;
    const int lr   = lane & 15;
    const int lq   = lane >> 4;
    const int n0   = blockIdx.x * 32;
    const f4 z4 = {0.f, 0.f, 0.f, 0.f};

    for (int i = t; i < 512; i += 256) {             // 32 rows x 16 granules
        int n = i >> 4, gr = i & 15;
        int nn = n0 + n; if (nn > NN - 1) nn = NN - 1;
        const float* sp = &emb[(size_t)z[nn] * FF + gr * 8];
        float4 aa = *(const float4*)sp;
        float4 bb = *(const float4*)(sp + 4);
        h8 hv;
        hv[0] = (_Float16)aa.x; hv[1] = (_Float16)aa.y;
        hv[2] = (_Float16)aa.z; hv[3] = (_Float16)aa.w;
        hv[4] = (_Float16)bb.x; hv[5] = (_Float16)bb.y;
        hv[6] = (_Float16)bb.z; hv[7] = (_Float16)bb.w;
        *(h8*)&Ss[(n * 16 + (gr ^ (n & 15))) * 8] = hv;
        *(h8*)&s_h[(size_t)nn * FF + gr * 8] = hv;
    }
    __syncthreads();

    f4 acc1[2][2];
    #pragma unroll
    for (int a = 0; a < 2; ++a)
        #pragma unroll
        for (int m = 0; m < 2; ++m) acc1[a][m] = z4;
    {
        const _Float16* bb = Wp1h + (size_t)lr * 128 + lq * 8;
        #pragma unroll
        for (int g2 = 0; g2 < 2; ++g2) {
            h8 bf[4];
            #pragma unroll
            for (int ks = 0; ks < 4; ++ks)
                bf[ks] = *(const h8*)(bb + ((2 * w + g2) * 16) * 128 + ks * 32);
            #pragma unroll
            for (int mt = 0; mt < 2; ++mt) {
                const int r = mt * 16 + lr;
                #pragma unroll
                for (int ks = 0; ks < 4; ++ks) {
                    h8 af = *(const h8*)&Ss[(r * 16 + ((ks * 4 + lq) ^ (r & 15))) * 8];
                    acc1[g2][mt] = __builtin_amdgcn_mfma_f32_16x16x32_f16(
                        af, bf[ks], acc1[g2][mt], 0, 0, 0);
                }
            }
        }
    }
    #pragma unroll
    for (int g2 = 0; g2 < 2; ++g2) {
        const int g = (2 * w + g2) * 16 + lr;
        const float b1 = bp1[g];
        #pragma unroll
        for (int mt = 0; mt < 2; ++mt)
            #pragma unroll
            for (int r = 0; r < 4; ++r) {
                float x = acc1[g2][mt][r] + b1;
                float y = x / (1.f + __expf(-x));
                int n = mt * 16 + lq * 4 + r;
                H1s[(n * 16 + ((g >> 3) ^ (n & 15))) * 8 + (g & 7)] = (_Float16)y;
            }
    }
    __syncthreads();

    f4 accS[2][2], accV[2][2];
    #pragma unroll
    for (int a = 0; a < 2; ++a)
        #pragma unroll
        for (int m = 0; m < 2; ++m) { accS[a][m] = z4; accV[a][m] = z4; }
    {
        const _Float16* bbs = Wp2h + (size_t)lr * 128 + lq * 8;
        const _Float16* bbv = Wp2h + (size_t)(256 + lr) * 128 + lq * 8;
        #pragma unroll
        for (int g2 = 0; g2 < 2; ++g2) {
            h8 bfs[4], bfv[4];
            #pragma unroll
            for (int ks = 0; ks < 4; ++ks) {
                bfs[ks] = *(const h8*)(bbs + ((2 * w + g2) * 16) * 128 + ks * 32);
                bfv[ks] = *(const h8*)(bbv + ((2 * w + g2) * 16) * 128 + ks * 32);
            }
            #pragma unroll
            for (int mt = 0; mt < 2; ++mt) {
                const int r = mt * 16 + lr;
                #pragma unroll
                for (int ks = 0; ks < 4; ++ks) {
                    h8 af = *(const h8*)&H1s[(r * 16 + ((ks * 4 + lq) ^ (r & 15))) * 8];
                    accS[g2][mt] = __builtin_amdgcn_mfma_f32_16x16x32_f16(
                        af, bfs[ks], accS[g2][mt], 0, 0, 0);
                    accV[g2][mt] = __builtin_amdgcn_mfma_f32_16x16x32_f16(
                        af, bfv[ks], accV[g2][mt], 0, 0, 0);
                }
            }
        }
    }
    #pragma unroll
    for (int g2 = 0; g2 < 2; ++g2) {
        const int g = (2 * w + g2) * 16 + lr;
        const float bsa = bp2[g], bva = bp2[256 + g];
        #pragma unroll
        for (int mt = 0; mt < 2; ++mt)
            #pragma unroll
            for (int r = 0; r < 4; ++r) {
                int n = mt * 16 + lq * 4 + r;
                int nn = n0 + n;
                if (nn < NN) {
                    pk32 pk;
                    pk.h[0] = (_Float16)(accS[g2][mt][r] + bsa);
                    pk.h[1] = (_Float16)(accV[g2][mt][r] + bva);
                    phi_pk[(size_t)nn * FF + g] = pk.u;
                }
            }
    }
}

// ---------------------------------------------------------------------------
// K2 (MFMA Wf): block-per-node (round-4-measured structure). s carried f16.
__global__ __launch_bounds__(128) void k_edge_mfma(
    const float* __restrict__ pos,
    const _Float16* __restrict__ Wwh32,
    const int* __restrict__ src,
    const int* __restrict__ counts, const int* __restrict__ slots,
    const unsigned int* __restrict__ phi_pk,
    _Float16* __restrict__ s_h,
    _Float16* __restrict__ xg)
{
    __shared__ _Float16 A[16 * 32];          // swizzled rbf A-tile (1 KB)
    __shared__ float dirs[16][4];            // ux, uy, uz, asfloat(sI)
    __shared__ float dls[16];                // distance per edge
    __shared__ unsigned int wf[16 * 130];    // interleaved {s,v} f16 Wf (8.3 KB)

    const int t    = threadIdx.x;
    const int lane = t & 63;
    const int w    = t >> 6;     // wave 0 = s-half, wave 1 = v-half
    const int lr   = lane & 15;
    const int lq   = lane >> 4;
    const int n    = blockIdx.x;
    const f4 z4 = {0.f, 0.f, 0.f, 0.f};

    // B-fragments: tile-invariant, loaded once (L2-hot).
    h8 bf[8];
    #pragma unroll
    for (int j = 0; j < 8; ++j)
        bf[j] = *(const h8*)&Wwh32[(size_t)((w * 8 + j) * 16 + lr) * 32 + lq * 8];

    const float px = pos[3 * n], py = pos[3 * n + 1], pz = pos[3 * n + 2];

    int deg = counts[n];
    deg = deg > MAXDEG ? MAXDEG : deg;

    float acc_s = 0.f, av0 = 0.f, av1 = 0.f, av2 = 0.f;

    for (int t0 = 0; t0 < deg; t0 += 16) {
        const int degT = (deg - t0) < 16 ? (deg - t0) : 16;
        __syncthreads();                       // guard LDS reuse
        // ---- phase 1: per-edge geometry (threads 0..degT-1) ----
        if (t < degT) {
            int e  = slots[n * MAXDEG + t0 + t];
            int sI = src[e];
            float rx = px - pos[3 * sI];
            float ry = py - pos[3 * sI + 1];
            float rz = pz - pos[3 * sI + 2];
            float d = sqrtf(rx * rx + ry * ry + rz * rz);
            d = fmaxf(d, 1e-9f);
            float di = 1.f / d;
            dirs[t][0] = rx * di;
            dirs[t][1] = ry * di;
            dirs[t][2] = rz * di;
            dirs[t][3] = __int_as_float(sI);
            dls[t] = d;
        }
        __syncthreads();
        // ---- phase 2: rbf -> A-tile. thread = (edge m = t&15, kk = t>>4) ----
        {
            const int m = t & 15, kk = t >> 4;
            float d  = dls[m];
            float di = 1.f / d;
            float v0 = __sinf((float)(kk + 1) * PI_OVER_CUT * d) * di;
            float v1 = __sinf((float)(kk + 9) * PI_OVER_CUT * d) * di;
            float v2;
            if (kk < 4)       v2 = __sinf((float)(kk + 17) * PI_OVER_CUT * d) * di;
            else if (kk == 4) v2 = 1.0f;     // k=20: bias element
            else              v2 = 0.f;
            // chunk-swizzled store: phys chunk = (k>>3) ^ (m&3)
            #define STO(K, V) A[m * 32 + (((K) >> 3) ^ (m & 3)) * 8 + ((K) & 7)] = (_Float16)(V)
            STO(kk,      v0);
            STO(kk + 8,  v1);
            STO(kk + 16, v2);
            STO(kk + 24, 0.f);
            #undef STO
        }
        __syncthreads();
        // ---- MFMA: Wf tile (each wave: 8 n-tiles of 16 features) ----
        {
            h8 af = *(const h8*)&A[(lr * 4 + (lq ^ (lr & 3))) * 8];
            #pragma unroll
            for (int j = 0; j < 8; ++j) {
                f4 dd = __builtin_amdgcn_mfma_f32_16x16x32_f16(af, bf[j], z4, 0, 0, 0);
                #pragma unroll
                for (int r = 0; r < 4; ++r) {
                    int m = lq * 4 + r;
                    ((_Float16*)&wf[m * 130 + j * 16 + lr])[w] = (_Float16)dd[r];
                }
            }
        }
        __syncthreads();
        // ---- accumulation over this tile's edges ----
        for (int m = 0; m < degT; ++m) {
            float4 dir = *(const float4*)&dirs[m][0];
            int sI = __builtin_amdgcn_readfirstlane(__float_as_int(dir.w));
            pk32 ph, wfu;
            ph.u  = phi_pk[(size_t)sI * FF + t];
            wfu.u = wf[m * 130 + t];
            float ps = (float)ph.h[0] * (float)wfu.h[0];
            float pv = (float)ph.h[1] * (float)wfu.h[1];
            acc_s += ps;
            av0 = fmaf(pv, dir.x, av0);
            av1 = fmaf(pv, dir.y, av1);
            av2 = fmaf(pv, dir.z, av2);
        }
    }

    size_t gi = (size_t)n * FF + t;
    float s_old = (float)s_h[gi];
    s_h[gi] = (_Float16)(s_old + acc_s);
    xg[((size_t)n * 3 + 0) * FF + t] = (_Float16)av0;
    xg[((size_t)n * 3 + 1) * FF + t] = (_Float16)av1;
    xg[((size_t)n * 3 + 2) * FF + t] = (_Float16)av2;
}

// ---------------------------------------------------------------------------
// K3: update block on f16 MFMA, 16 nodes/block (fewer regs + LDS -> more
// resident waves for this latency-bound kernel). Residuals from staged f16
// LDS tiles; s staged directly from f16 s_h. v_io/s_io write-only.
__global__ __launch_bounds__(256) void k_update_mfma(
    const _Float16* __restrict__ xg, const _Float16* __restrict__ s_h,
    const _Float16* __restrict__ Wuh, const _Float16* __restrict__ Wvh,
    const _Float16* __restrict__ Wu1h, const _Float16* __restrict__ Wu2h,
    const float* __restrict__ bu, const float* __restrict__ bv,
    const float* __restrict__ bu1, const float* __restrict__ bu2,
    float* __restrict__ s_io, float* __restrict__ v_io)
{
    __shared__ _Float16 Xs[48 * 128];    // A for GEMM1: row = c*16+n, k = f (12 KB)
    __shared__ _Float16 Hs[16 * 256];    // A for GEMM2: [s | Vn]          (8 KB)
    __shared__ _Float16 H1s[16 * 128];   // A for GEMM3                    (4 KB)

    const int t    = threadIdx.x;
    const int lane = t & 63;
    const int w    = t >> 6;     // wave 0..3
    const int lr   = lane & 15;  // A-row / B-col within tile
    const int lq   = lane >> 4;  // k-chunk selector
    const int n0   = blockIdx.x * 16;
    const f4 z4 = {0.f, 0.f, 0.f, 0.f};

    // ---- stage Xs from xg (48 rows x 16 granules) ----
    for (int i = t; i < 768; i += 256) {
        int row = i >> 4, gr = i & 15;
        int n = row & 15, c = row >> 4;
        int nn = n0 + n; if (nn > NN - 1) nn = NN - 1;
        uint4 d = *(const uint4*)&xg[((size_t)nn * 3 + c) * FF + gr * 8];
        *(uint4*)&Xs[(row * 16 + (gr ^ n)) * 8] = d;
    }
    // ---- stage s (f16 direct) -> Hs[:, 0:128) : 16 rows x 16 granules ----
    {
        int n = t >> 4, gr = t & 15;
        int nn = n0 + n; if (nn > NN - 1) nn = NN - 1;
        uint4 d = *(const uint4*)&s_h[(size_t)nn * FF + gr * 8];
        *(uint4*)&Hs[(n * 32 + (gr ^ n)) * 8] = d;
    }
    __syncthreads();

    // ---- GEMM1: U,V[c*16+n][g] ----
    f4 accU[2][3], accV[2][3];   // [g-subtile][c]
    #pragma unroll
    for (int a = 0; a < 2; ++a)
        #pragma unroll
        for (int c = 0; c < 3; ++c) { accU[a][c] = z4; accV[a][c] = z4; }

    {   // U pass
        const _Float16* bb = Wuh + (size_t)lr * 128 + lq * 8;
        h8 bfr[2][4];
        #pragma unroll
        for (int g2 = 0; g2 < 2; ++g2)
            #pragma unroll
            for (int ks = 0; ks < 4; ++ks)
                bfr[g2][ks] = *(const h8*)(bb + ((2 * w + g2) * 16) * 128 + ks * 32);
        #pragma unroll
        for (int c = 0; c < 3; ++c) {
            const int rr = c * 16 + lr;
            h8 af[4];
            #pragma unroll
            for (int ks = 0; ks < 4; ++ks)
                af[ks] = *(const h8*)&Xs[(rr * 16 + ((ks * 4 + lq) ^ lr)) * 8];
            #pragma unroll
            for (int g2 = 0; g2 < 2; ++g2)
                #pragma unroll
                for (int ks = 0; ks < 4; ++ks)
                    accU[g2][c] = __builtin_amdgcn_mfma_f32_16x16x32_f16(
                        af[ks], bfr[g2][ks], accU[g2][c], 0, 0, 0);
        }
    }
    {   // V pass
        const _Float16* bb = Wvh + (size_t)lr * 128 + lq * 8;
        h8 bfr[2][4];
        #pragma unroll
        for (int g2 = 0; g2 < 2; ++g2)
            #pragma unroll
            for (int ks = 0; ks < 4; ++ks)
                bfr[g2][ks] = *(const h8*)(bb + ((2 * w + g2) * 16) * 128 + ks * 32);
        #pragma unroll
        for (int c = 0; c < 3; ++c) {
            const int rr = c * 16 + lr;
            h8 af[4];
            #pragma unroll
            for (int ks = 0; ks < 4; ++ks)
                af[ks] = *(const h8*)&Xs[(rr * 16 + ((ks * 4 + lq) ^ lr)) * 8];
            #pragma unroll
            for (int g2 = 0; g2 < 2; ++g2)
                #pragma unroll
                for (int ks = 0; ks < 4; ++ks)
                    accV[g2][c] = __builtin_amdgcn_mfma_f32_16x16x32_f16(
                        af[ks], bfr[g2][ks], accV[g2][c], 0, 0, 0);
        }
    }

    // ---- epilogue 1: bias, u.v, Vn -> Hs[:,128:256) ----
    float uvr[2][4];
    #pragma unroll
    for (int g2 = 0; g2 < 2; ++g2) {
        const int g = (2 * w + g2) * 16 + lr;
        const float bU = bu[g], bV = bv[g];
        #pragma unroll
        for (int r = 0; r < 4; ++r) {
            float Ux = accU[g2][0][r] + bU;
            float Uy = accU[g2][1][r] + bU;
            float Uz = accU[g2][2][r] + bU;
            float Vx = accV[g2][0][r] + bV;
            float Vy = accV[g2][1][r] + bV;
            float Vz = accV[g2][2][r] + bV;
            accU[g2][0][r] = Ux;
            accU[g2][1][r] = Uy;
            accU[g2][2][r] = Uz;
            uvr[g2][r] = Ux * Vx + Uy * Vy + Uz * Vz;
            float vn = sqrtf(Vx * Vx + Vy * Vy + Vz * Vz);
            int n = lq * 4 + r;
            int gr = 16 + (g >> 3);
            Hs[(n * 32 + (gr ^ n)) * 8 + (g & 7)] = (_Float16)vn;
        }
    }
    __syncthreads();

    // ---- GEMM2: h1 = silu(Wu1 @ [s;Vn] + bu1) (single 16-row tile) ----
    f4 acc2[2];
    acc2[0] = z4; acc2[1] = z4;
    {
        const _Float16* bb = Wu1h + (size_t)lr * 256 + lq * 8;
        #pragma unroll
        for (int g2 = 0; g2 < 2; ++g2) {
            h8 bfr[8];
            #pragma unroll
            for (int ks = 0; ks < 8; ++ks)
                bfr[ks] = *(const h8*)(bb + ((2 * w + g2) * 16) * 256 + ks * 32);
            #pragma unroll
            for (int ks = 0; ks < 8; ++ks) {
                h8 af = *(const h8*)&Hs[(lr * 32 + ((ks * 4 + lq) ^ lr)) * 8];
                acc2[g2] = __builtin_amdgcn_mfma_f32_16x16x32_f16(
                    af, bfr[ks], acc2[g2], 0, 0, 0);
            }
        }
    }
    #pragma unroll
    for (int g2 = 0; g2 < 2; ++g2) {
        const int g = (2 * w + g2) * 16 + lr;
        const float b1 = bu1[g];
        #pragma unroll
        for (int r = 0; r < 4; ++r) {
            float x = acc2[g2][r] + b1;
            float y = x / (1.f + __expf(-x));
            int n = lq * 4 + r;
            H1s[(n * 16 + ((g >> 3) ^ n)) * 8 + (g & 7)] = (_Float16)y;
        }
    }
    __syncthreads();

    // ---- GEMM3: a = Wu2 @ h1 + bu2 (single 16-row tile) ----
    f4 acc3[3][2];
    #pragma unroll
    for (int a = 0; a < 3; ++a) { acc3[a][0] = z4; acc3[a][1] = z4; }
    {
        const _Float16* bb = Wu2h + (size_t)lr * 128 + lq * 8;
        #pragma unroll
        for (int ai = 0; ai < 3; ++ai)
            #pragma unroll
            for (int g2 = 0; g2 < 2; ++g2) {
                const int jt = ai * 8 + 2 * w + g2;
                h8 bfr[4];
                #pragma unroll
                for (int ks = 0; ks < 4; ++ks)
                    bfr[ks] = *(const h8*)(bb + (size_t)(jt * 16) * 128 + ks * 32);
                #pragma unroll
                for (int ks = 0; ks < 4; ++ks) {
                    h8 af = *(const h8*)&H1s[(lr * 16 + ((ks * 4 + lq) ^ lr)) * 8];
                    acc3[ai][g2] = __builtin_amdgcn_mfma_f32_16x16x32_f16(
                        af, bfr[ks], acc3[ai][g2], 0, 0, 0);
                }
            }
    }

    // ---- final epilogue: residuals from staged f16 LDS tiles ----
    #pragma unroll
    for (int g2 = 0; g2 < 2; ++g2) {
        const int g = (2 * w + g2) * 16 + lr;
        const float b1 = bu2[g], b2 = bu2[128 + g], b3 = bu2[256 + g];
        #pragma unroll
        for (int r = 0; r < 4; ++r) {
            int n = lq * 4 + r;
            int nn = n0 + n;
            if (nn < NN) {
                float a1 = acc3[0][g2][r] + b1;
                float a2 = acc3[1][g2][r] + b2;
                float a3 = acc3[2][g2][r] + b3;
                size_t gi = (size_t)nn * FF + g;
                float s1 = (float)Hs[(n * 32 + ((g >> 3) ^ n)) * 8 + (g & 7)];
                s_io[gi] = s1 + a2 + uvr[g2][r] * a3;
                float vx = (float)Xs[((0 * 16 + n) * 16 + ((g >> 3) ^ n)) * 8 + (g & 7)];
                float vy = (float)Xs[((1 * 16 + n) * 16 + ((g >> 3) ^ n)) * 8 + (g & 7)];
                float vz = (float)Xs[((2 * 16 + n) * 16 + ((g >> 3) ^ n)) * 8 + (g & 7)];
                v_io[gi * 3 + 0] = vx + accU[g2][0][r] * a1;
                v_io[gi * 3 + 1] = vy + accU[g2][1][r] * a1;
                v_io[gi * 3 + 2] = vz + accU[g2][2][r] * a1;
            }
        }
    }
}

// ---------------------------------------------------------------------------
extern "C" void kernel_launch(void* const* d_in, const int* in_sizes, int n_in,
                              void* d_out, int out_size, void* d_ws, size_t ws_size,
                              hipStream_t stream)
{
    const float* pos = (const float*)d_in[0];
    const float* emb = (const float*)d_in[1];
    const float* Wp1 = (const float*)d_in[2];
    const float* bp1 = (const float*)d_in[3];
    const float* Wp2 = (const float*)d_in[4];
    const float* bp2 = (const float*)d_in[5];
    const float* Ww  = (const float*)d_in[6];
    const float* bw  = (const float*)d_in[7];
    const float* Wu  = (const float*)d_in[8];
    const float* bu  = (const float*)d_in[9];
    const float* Wv  = (const float*)d_in[10];
    const float* bv  = (const float*)d_in[11];
    const float* Wu1 = (const float*)d_in[12];
    const float* bu1 = (const float*)d_in[13];
    const float* Wu2 = (const float*)d_in[14];
    const float* bu2 = (const float*)d_in[15];
    const int* z   = (const int*)d_in[16];
    const int* src = (const int*)d_in[17];
    const int* dst = (const int*)d_in[18];

    float* s_io = (float*)d_out;
    float* v_io = (float*)d_out + (size_t)NN * FF;

    char* ws = (char*)d_ws;
    unsigned int* phi_pk = (unsigned int*)ws;                 // NN*FF uints
    _Float16* xg    = (_Float16*)(phi_pk + (size_t)NN * FF);  // NN*3*FF
    _Float16* s_h   = xg + (size_t)NN * 3 * FF;               // NN*FF
    _Float16* Wuh   = s_h + (size_t)NN * FF;
    _Float16* Wvh   = Wuh  + 128 * 128;
    _Float16* Wu1h  = Wvh  + 128 * 128;
    _Float16* Wu2h  = Wu1h + 128 * 256;
    _Float16* Wp1h  = Wu2h + 384 * 128;
    _Float16* Wp2h  = Wp1h + 128 * 128;
    _Float16* Wwh32 = Wp2h + 384 * 128;                       // 256*32
    int* counts = (int*)(Wwh32 + 256 * 32);
    int* slots  = counts + NN;

    k_wconv <<<196, 256, 0, stream>>>(Wu, Wv, Wu1, Wu2, Wp1, Wp2, Ww, bw,
                                      Wuh, Wvh, Wu1h, Wu2h, Wp1h, Wp2h, Wwh32,
                                      counts);
    k_bucket<<<(EE + 255) / 256, 256, 0, stream>>>(dst, counts, slots);
    k_node_phi_mfma<<<(NN + 31) / 32, 256, 0, stream>>>(emb, z, Wp1h, bp1,
                                                        Wp2h, bp2,
                                                        phi_pk, s_h);
    k_edge_mfma<<<NN, 128, 0, stream>>>(pos, Wwh32, src, counts, slots,
                                        phi_pk, s_h, xg);
    k_update_mfma<<<(NN + 15) / 16, 256, 0, stream>>>(xg, s_h,
                                                      Wuh, Wvh, Wu1h, Wu2h,
                                                      bu, bv, bu1, bu2,
                                                      s_io, v_io);
}

// Round 7
// 382.152 us; speedup vs baseline: 1.0441x; 1.0167x over previous
//
#include <hip/hip_runtime.h>

#define NN 50000
#define EE 400000
#define FF 128
#define NRBF 20
#define MAXDEG 64
#define PI_OVER_CUT 0.6283185307179586f   // pi / 5.0

typedef _Float16 h8 __attribute__((ext_vector_type(8)));
typedef float    f4 __attribute__((ext_vector_type(4)));

union pk32 { unsigned int u; _Float16 h[2]; };

// ---------------------------------------------------------------------------
__global__ __launch_bounds__(256) void k_bucket(const int* __restrict__ dst,
                                                int* __restrict__ counts,
                                                int* __restrict__ slots) {
    int e = blockIdx.x * 256 + threadIdx.x;
    if (e < EE) {
        int n = dst[e];
        int slot = atomicAdd(&counts[n], 1);
        if (slot < MAXDEG) slots[n * MAXDEG + slot] = e;
    }
}

// Convert all GEMM weights to f16 once; also zeroes counts (merged k_zero).
__global__ __launch_bounds__(256) void k_wconv(
    const float* __restrict__ Wu, const float* __restrict__ Wv,
    const float* __restrict__ Wu1, const float* __restrict__ Wu2,
    const float* __restrict__ Wp1, const float* __restrict__ Wp2,
    const float* __restrict__ Ww, const float* __restrict__ bw,
    _Float16* __restrict__ Wuh, _Float16* __restrict__ Wvh,
    _Float16* __restrict__ Wu1h, _Float16* __restrict__ Wu2h,
    _Float16* __restrict__ Wp1h, _Float16* __restrict__ Wp2h,
    _Float16* __restrict__ Wwh32, int* __restrict__ counts)
{
    int i = blockIdx.x * 256 + threadIdx.x;
    if (i < NN) counts[i] = 0;
    if (i < 16384) { Wuh[i] = (_Float16)Wu[i]; Wvh[i] = (_Float16)Wv[i];
                     Wp1h[i] = (_Float16)Wp1[i]; }
    if (i < 32768) { Wu1h[i] = (_Float16)Wu1[i]; }
    if (i < 49152) { Wu2h[i] = (_Float16)Wu2[i]; Wp2h[i] = (_Float16)Wp2[i]; }
    if (i < 8192) {
        int col = i >> 5, k = i & 31;
        int sr = col < 128 ? col : col + 128;
        _Float16 v = (_Float16)0.f;
        if (k < 20)       v = (_Float16)Ww[sr * NRBF + k];
        else if (k == 20) v = (_Float16)bw[sr];
        Wwh32[i] = v;
    }
}

// ---------------------------------------------------------------------------
// K1 (MFMA): s0 = emb[z]; h1 = silu(Wp1 s + bp1); phi = Wp2 h1 + bp2.
// s0 carried forward as f16 (s_h).
__global__ __launch_bounds__(256) void k_node_phi_mfma(
    const float* __restrict__ emb, const int* __restrict__ z,
    const _Float16* __restrict__ Wp1h, const float* __restrict__ bp1,
    const _Float16* __restrict__ Wp2h, const float* __restrict__ bp2,
    unsigned int* __restrict__ phi_pk, _Float16* __restrict__ s_h)
{
    __shared__ _Float16 Ss[32 * 128];
    __shared__ _Float16 H1s[32 * 128];

    const int t    = threadIdx.x;
    const int lane = t & 63;
    const int w    = t >> 6;
    const int lr   = lane & 15;
    const int lq   = lane >> 4;
    const int n0   = blockIdx.x * 32;
    const f4 z4 = {0.f, 0.f, 0.f, 0.f};

    for (int i = t; i < 512; i += 256) {             // 32 rows x 16 granules
        int n = i >> 4, gr = i & 15;
        int nn = n0 + n; if (nn > NN - 1) nn = NN - 1;
        const float* sp = &emb[(size_t)z[nn] * FF + gr * 8];
        float4 aa = *(const float4*)sp;
        float4 bb = *(const float4*)(sp + 4);
        h8 hv;
        hv[0] = (_Float16)aa.x; hv[1] = (_Float16)aa.y;
        hv[2] = (_Float16)aa.z; hv[3] = (_Float16)aa.w;
        hv[4] = (_Float16)bb.x; hv[5] = (_Float16)bb.y;
        hv[6] = (_Float16)bb.z; hv[7] = (_Float16)bb.w;
        *(h8*)&Ss[(n * 16 + (gr ^ (n & 15))) * 8] = hv;
        *(h8*)&s_h[(size_t)nn * FF + gr * 8] = hv;
    }
    __syncthreads();

    f4 acc1[2][2];
    #pragma unroll
    for (int a = 0; a < 2; ++a)
        #pragma unroll
        for (int m = 0; m < 2; ++m) acc1[a][m] = z4;
    {
        const _Float16* bb = Wp1h + (size_t)lr * 128 + lq * 8;
        #pragma unroll
        for (int g2 = 0; g2 < 2; ++g2) {
            h8 bf[4];
            #pragma unroll
            for (int ks = 0; ks < 4; ++ks)
                bf[ks] = *(const h8*)(bb + ((2 * w + g2) * 16) * 128 + ks * 32);
            #pragma unroll
            for (int mt = 0; mt < 2; ++mt) {
                const int r = mt * 16 + lr;
                #pragma unroll
                for (int ks = 0; ks < 4; ++ks) {
                    h8 af = *(const h8*)&Ss[(r * 16 + ((ks * 4 + lq) ^ (r & 15))) * 8];
                    acc1[g2][mt] = __builtin_amdgcn_mfma_f32_16x16x32_f16(
                        af, bf[ks], acc1[g2][mt], 0, 0, 0);
                }
            }
        }
    }
    #pragma unroll
    for (int g2 = 0; g2 < 2; ++g2) {
        const int g = (2 * w + g2) * 16 + lr;
        const float b1 = bp1[g];
        #pragma unroll
        for (int mt = 0; mt < 2; ++mt)
            #pragma unroll
            for (int r = 0; r < 4; ++r) {
                float x = acc1[g2][mt][r] + b1;
                float y = x / (1.f + __expf(-x));
                int n = mt * 16 + lq * 4 + r;
                H1s[(n * 16 + ((g >> 3) ^ (n & 15))) * 8 + (g & 7)] = (_Float16)y;
            }
    }
    __syncthreads();

    f4 accS[2][2], accV[2][2];
    #pragma unroll
    for (int a = 0; a < 2; ++a)
        #pragma unroll
        for (int m = 0; m < 2; ++m) { accS[a][m] = z4; accV[a][m] = z4; }
    {
        const _Float16* bbs = Wp2h + (size_t)lr * 128 + lq * 8;
        const _Float16* bbv = Wp2h + (size_t)(256 + lr) * 128 + lq * 8;
        #pragma unroll
        for (int g2 = 0; g2 < 2; ++g2) {
            h8 bfs[4], bfv[4];
            #pragma unroll
            for (int ks = 0; ks < 4; ++ks) {
                bfs[ks] = *(const h8*)(bbs + ((2 * w + g2) * 16) * 128 + ks * 32);
                bfv[ks] = *(const h8*)(bbv + ((2 * w + g2) * 16) * 128 + ks * 32);
            }
            #pragma unroll
            for (int mt = 0; mt < 2; ++mt) {
                const int r = mt * 16 + lr;
                #pragma unroll
                for (int ks = 0; ks < 4; ++ks) {
                    h8 af = *(const h8*)&H1s[(r * 16 + ((ks * 4 + lq) ^ (r & 15))) * 8];
                    accS[g2][mt] = __builtin_amdgcn_mfma_f32_16x16x32_f16(
                        af, bfs[ks], accS[g2][mt], 0, 0, 0);
                    accV[g2][mt] = __builtin_amdgcn_mfma_f32_16x16x32_f16(
                        af, bfv[ks], accV[g2][mt], 0, 0, 0);
                }
            }
        }
    }
    #pragma unroll
    for (int g2 = 0; g2 < 2; ++g2) {
        const int g = (2 * w + g2) * 16 + lr;
        const float bsa = bp2[g], bva = bp2[256 + g];
        #pragma unroll
        for (int mt = 0; mt < 2; ++mt)
            #pragma unroll
            for (int r = 0; r < 4; ++r) {
                int n = mt * 16 + lq * 4 + r;
                int nn = n0 + n;
                if (nn < NN) {
                    pk32 pk;
                    pk.h[0] = (_Float16)(accS[g2][mt][r] + bsa);
                    pk.h[1] = (_Float16)(accV[g2][mt][r] + bva);
                    phi_pk[(size_t)nn * FF + g] = pk.u;
                }
            }
    }
}

// ---------------------------------------------------------------------------
// K2 (MFMA Wf): block-per-node. Fused geometry+rbf phase (all 128 threads,
// 8-way redundant per edge, wave-broadcast loads); batched 16-wide phi
// gathers; early s_h read.
__global__ __launch_bounds__(128) void k_edge_mfma(
    const float* __restrict__ pos,
    const _Float16* __restrict__ Wwh32,
    const int* __restrict__ src,
    const int* __restrict__ counts, const int* __restrict__ slots,
    const unsigned int* __restrict__ phi_pk,
    _Float16* __restrict__ s_h,
    _Float16* __restrict__ xg)
{
    __shared__ _Float16 A[16 * 32];          // swizzled rbf A-tile (1 KB)
    __shared__ float dirs[16][4];            // ux, uy, uz, asfloat(sI)
    __shared__ unsigned int wf[16 * 130];    // interleaved {s,v} f16 Wf (8.3 KB)

    const int t    = threadIdx.x;
    const int lane = t & 63;
    const int w    = t >> 6;     // wave 0 = s-half, wave 1 = v-half
    const int lr   = lane & 15;
    const int lq   = lane >> 4;
    const int n    = blockIdx.x;
    const int m    = t & 15;     // edge slot this thread serves
    const int kk   = t >> 4;     // rbf k-slot
    const f4 z4 = {0.f, 0.f, 0.f, 0.f};

    // B-fragments: tile-invariant, loaded once (L2-hot).
    h8 bf[8];
    #pragma unroll
    for (int j = 0; j < 8; ++j)
        bf[j] = *(const h8*)&Wwh32[(size_t)((w * 8 + j) * 16 + lr) * 32 + lq * 8];

    const float px = pos[3 * n], py = pos[3 * n + 1], pz = pos[3 * n + 2];

    int deg = counts[n];
    deg = deg > MAXDEG ? MAXDEG : deg;

    const size_t gi = (size_t)n * FF + t;
    float s_old = (float)s_h[gi];            // issued early, used at the end

    float acc_s = 0.f, av0 = 0.f, av1 = 0.f, av2 = 0.f;

    for (int t0 = 0; t0 < deg; t0 += 16) {
        const int degT = (deg - t0) < 16 ? (deg - t0) : 16;
        __syncthreads();                     // prev iteration's LDS reads done
        // ---- fused geometry + rbf: all threads, 8 per edge (broadcast) ----
        {
            int mc = (m < degT) ? m : 0;     // clamp to a valid edge
            int e  = slots[n * MAXDEG + t0 + mc];
            int sI = src[e];
            float rx = px - pos[3 * sI];
            float ry = py - pos[3 * sI + 1];
            float rz = pz - pos[3 * sI + 2];
            float d = sqrtf(rx * rx + ry * ry + rz * rz);
            d = fmaxf(d, 1e-9f);
            float di = 1.f / d;
            if (t < 16) {
                dirs[t][0] = rx * di;
                dirs[t][1] = ry * di;
                dirs[t][2] = rz * di;
                dirs[t][3] = __int_as_float(sI);
            }
            float v0 = __sinf((float)(kk + 1) * PI_OVER_CUT * d) * di;
            float v1 = __sinf((float)(kk + 9) * PI_OVER_CUT * d) * di;
            float v2;
            if (kk < 4)       v2 = __sinf((float)(kk + 17) * PI_OVER_CUT * d) * di;
            else if (kk == 4) v2 = 1.0f;     // k=20: bias element
            else              v2 = 0.f;
            // chunk-swizzled store: phys chunk = (k>>3) ^ (m&3)
            #define STO(K, V) A[m * 32 + (((K) >> 3) ^ (m & 3)) * 8 + ((K) & 7)] = (_Float16)(V)
            STO(kk,      v0);
            STO(kk + 8,  v1);
            STO(kk + 16, v2);
            STO(kk + 24, 0.f);
            #undef STO
        }
        __syncthreads();
        // ---- MFMA: Wf tile (each wave: 8 n-tiles of 16 features) ----
        {
            h8 af = *(const h8*)&A[(lr * 4 + (lq ^ (lr & 3))) * 8];
            #pragma unroll
            for (int j = 0; j < 8; ++j) {
                f4 dd = __builtin_amdgcn_mfma_f32_16x16x32_f16(af, bf[j], z4, 0, 0, 0);
                #pragma unroll
                for (int r = 0; r < 4; ++r) {
                    int mm = lq * 4 + r;
                    ((_Float16*)&wf[mm * 130 + j * 16 + lr])[w] = (_Float16)dd[r];
                }
            }
        }
        __syncthreads();
        // ---- batched 16-wide phi gathers, then FMA pass ----
        {
            unsigned int phr[16];
            #pragma unroll
            for (int mm = 0; mm < 16; ++mm) {
                int sim = __float_as_int(dirs[mm][3]);
                phr[mm] = (mm < degT) ? phi_pk[(size_t)sim * FF + t] : 0u;
            }
            #pragma unroll
            for (int mm = 0; mm < 16; ++mm) {
                if (mm < degT) {
                    pk32 ph, wfu;
                    ph.u  = phr[mm];
                    wfu.u = wf[mm * 130 + t];
                    float ps = (float)ph.h[0] * (float)wfu.h[0];
                    float pv = (float)ph.h[1] * (float)wfu.h[1];
                    acc_s += ps;
                    av0 = fmaf(pv, dirs[mm][0], av0);
                    av1 = fmaf(pv, dirs[mm][1], av1);
                    av2 = fmaf(pv, dirs[mm][2], av2);
                }
            }
        }
    }

    s_h[gi] = (_Float16)(s_old + acc_s);
    xg[((size_t)n * 3 + 0) * FF + t] = (_Float16)av0;
    xg[((size_t)n * 3 + 1) * FF + t] = (_Float16)av1;
    xg[((size_t)n * 3 + 2) * FF + t] = (_Float16)av2;
}

// ---------------------------------------------------------------------------
// K3: update block on f16 MFMA, 16 nodes/block. Residuals from staged f16
// LDS tiles; s staged directly from f16 s_h. s_io/v_io write-only.
__global__ __launch_bounds__(256) void k_update_mfma(
    const _Float16* __restrict__ xg, const _Float16* __restrict__ s_h,
    const _Float16* __restrict__ Wuh, const _Float16* __restrict__ Wvh,
    const _Float16* __restrict__ Wu1h, const _Float16* __restrict__ Wu2h,
    const float* __restrict__ bu, const float* __restrict__ bv,
    const float* __restrict__ bu1, const float* __restrict__ bu2,
    float* __restrict__ s_io, float* __restrict__ v_io)
{
    __shared__ _Float16 Xs[48 * 128];    // A for GEMM1: row = c*16+n, k = f (12 KB)
    __shared__ _Float16 Hs[16 * 256];    // A for GEMM2: [s | Vn]          (8 KB)
    __shared__ _Float16 H1s[16 * 128];   // A for GEMM3                    (4 KB)

    const int t    = threadIdx.x;
    const int lane = t & 63;
    const int w    = t >> 6;     // wave 0..3
    const int lr   = lane & 15;  // A-row / B-col within tile
    const int lq   = lane >> 4;  // k-chunk selector
    const int n0   = blockIdx.x * 16;
    const f4 z4 = {0.f, 0.f, 0.f, 0.f};

    // ---- stage Xs from xg (48 rows x 16 granules) ----
    for (int i = t; i < 768; i += 256) {
        int row = i >> 4, gr = i & 15;
        int n = row & 15, c = row >> 4;
        int nn = n0 + n; if (nn > NN - 1) nn = NN - 1;
        uint4 d = *(const uint4*)&xg[((size_t)nn * 3 + c) * FF + gr * 8];
        *(uint4*)&Xs[(row * 16 + (gr ^ n)) * 8] = d;
    }
    // ---- stage s (f16 direct) -> Hs[:, 0:128) : 16 rows x 16 granules ----
    {
        int n = t >> 4, gr = t & 15;
        int nn = n0 + n; if (nn > NN - 1) nn = NN - 1;
        uint4 d = *(const uint4*)&s_h[(size_t)nn * FF + gr * 8];
        *(uint4*)&Hs[(n * 32 + (gr ^ n)) * 8] = d;
    }
    __syncthreads();

    // ---- GEMM1: U,V[c*16+n][g] ----
    f4 accU[2][3], accV[2][3];   // [g-subtile][c]
    #pragma unroll
    for (int a = 0; a < 2; ++a)
        #pragma unroll
        for (int c = 0; c < 3; ++c) { accU[a][c] = z4; accV[a][c] = z4; }

    {   // U pass
        const _Float16* bb = Wuh + (size_t)lr * 128 + lq * 8;
        h8 bfr[2][4];
        #pragma unroll
        for (int g2 = 0; g2 < 2; ++g2)
            #pragma unroll
            for (int ks = 0; ks < 4; ++ks)
                bfr[g2][ks] = *(const h8*)(bb + ((2 * w + g2) * 16) * 128 + ks * 32);
        #pragma unroll
        for (int c = 0; c < 3; ++c) {
            const int rr = c * 16 + lr;
            h8 af[4];
            #pragma unroll
            for (int ks = 0; ks < 4; ++ks)
                af[ks] = *(const h8*)&Xs[(rr * 16 + ((ks * 4 + lq) ^ lr)) * 8];
            #pragma unroll
            for (int g2 = 0; g2 < 2; ++g2)
                #pragma unroll
                for (int ks = 0; ks < 4; ++ks)
                    accU[g2][c] = __builtin_amdgcn_mfma_f32_16x16x32_f16(
                        af[ks], bfr[g2][ks], accU[g2][c], 0, 0, 0);
        }
    }
    {   // V pass
        const _Float16* bb = Wvh + (size_t)lr * 128 + lq * 8;
        h8 bfr[2][4];
        #pragma unroll
        for (int g2 = 0; g2 < 2; ++g2)
            #pragma unroll
            for (int ks = 0; ks < 4; ++ks)
                bfr[g2][ks] = *(const h8*)(bb + ((2 * w + g2) * 16) * 128 + ks * 32);
        #pragma unroll
        for (int c = 0; c < 3; ++c) {
            const int rr = c * 16 + lr;
            h8 af[4];
            #pragma unroll
            for (int ks = 0; ks < 4; ++ks)
                af[ks] = *(const h8*)&Xs[(rr * 16 + ((ks * 4 + lq) ^ lr)) * 8];
            #pragma unroll
            for (int g2 = 0; g2 < 2; ++g2)
                #pragma unroll
                for (int ks = 0; ks < 4; ++ks)
                    accV[g2][c] = __builtin_amdgcn_mfma_f32_16x16x32_f16(
                        af[ks], bfr[g2][ks], accV[g2][c], 0, 0, 0);
        }
    }

    // ---- epilogue 1: bias, u.v, Vn -> Hs[:,128:256) ----
    float uvr[2][4];
    #pragma unroll
    for (int g2 = 0; g2 < 2; ++g2) {
        const int g = (2 * w + g2) * 16 + lr;
        const float bU = bu[g], bV = bv[g];
        #pragma unroll
        for (int r = 0; r < 4; ++r) {
            float Ux = accU[g2][0][r] + bU;
            float Uy = accU[g2][1][r] + bU;
            float Uz = accU[g2][2][r] + bU;
            float Vx = accV[g2][0][r] + bV;
            float Vy = accV[g2][1][r] + bV;
            float Vz = accV[g2][2][r] + bV;
            accU[g2][0][r] = Ux;
            accU[g2][1][r] = Uy;
            accU[g2][2][r] = Uz;
            uvr[g2][r] = Ux * Vx + Uy * Vy + Uz * Vz;
            float vn = sqrtf(Vx * Vx + Vy * Vy + Vz * Vz);
            int n = lq * 4 + r;
            int gr = 16 + (g >> 3);
            Hs[(n * 32 + (gr ^ n)) * 8 + (g & 7)] = (_Float16)vn;
        }
    }
    __syncthreads();

    // ---- GEMM2: h1 = silu(Wu1 @ [s;Vn] + bu1) (single 16-row tile) ----
    f4 acc2[2];
    acc2[0] = z4; acc2[1] = z4;
    {
        const _Float16* bb = Wu1h + (size_t)lr * 256 + lq * 8;
        #pragma unroll
        for (int g2 = 0; g2 < 2; ++g2) {
            h8 bfr[8];
            #pragma unroll
            for (int ks = 0; ks < 8; ++ks)
                bfr[ks] = *(const h8*)(bb + ((2 * w + g2) * 16) * 256 + ks * 32);
            #pragma unroll
            for (int ks = 0; ks < 8; ++ks) {
                h8 af = *(const h8*)&Hs[(lr * 32 + ((ks * 4 + lq) ^ lr)) * 8];
                acc2[g2] = __builtin_amdgcn_mfma_f32_16x16x32_f16(
                    af, bfr[ks], acc2[g2], 0, 0, 0);
            }
        }
    }
    #pragma unroll
    for (int g2 = 0; g2 < 2; ++g2) {
        const int g = (2 * w + g2) * 16 + lr;
        const float b1 = bu1[g];
        #pragma unroll
        for (int r = 0; r < 4; ++r) {
            float x = acc2[g2][r] + b1;
            float y = x / (1.f + __expf(-x));
            int n = lq * 4 + r;
            H1s[(n * 16 + ((g >> 3) ^ n)) * 8 + (g & 7)] = (_Float16)y;
        }
    }
    __syncthreads();

    // ---- GEMM3: a = Wu2 @ h1 + bu2 (single 16-row tile) ----
    f4 acc3[3][2];
    #pragma unroll
    for (int a = 0; a < 3; ++a) { acc3[a][0] = z4; acc3[a][1] = z4; }
    {
        const _Float16* bb = Wu2h + (size_t)lr * 128 + lq * 8;
        #pragma unroll
        for (int ai = 0; ai < 3; ++ai)
            #pragma unroll
            for (int g2 = 0; g2 < 2; ++g2) {
                const int jt = ai * 8 + 2 * w + g2;
                h8 bfr[4];
                #pragma unroll
                for (int ks = 0; ks < 4; ++ks)
                    bfr[ks] = *(const h8*)(bb + (size_t)(jt * 16) * 128 + ks * 32);
                #pragma unroll
                for (int ks = 0; ks < 4; ++ks) {
                    h8 af = *(const h8*)&H1s[(lr * 16 + ((ks * 4 + lq) ^ lr)) * 8];
                    acc3[ai][g2] = __builtin_amdgcn_mfma_f32_16x16x32_f16(
                        af, bfr[ks], acc3[ai][g2], 0, 0, 0);
                }
            }
    }

    // ---- final epilogue: residuals from staged f16 LDS tiles ----
    #pragma unroll
    for (int g2 = 0; g2 < 2; ++g2) {
        const int g = (2 * w + g2) * 16 + lr;
        const float b1 = bu2[g], b2 = bu2[128 + g], b3 = bu2[256 + g];
        #pragma unroll
        for (int r = 0; r < 4; ++r) {
            int n = lq * 4 + r;
            int nn = n0 + n;
            if (nn < NN) {
                float a1 = acc3[0][g2][r] + b1;
                float a2 = acc3[1][g2][r] + b2;
                float a3 = acc3[2][g2][r] + b3;
                size_t gi = (size_t)nn * FF + g;
                float s1 = (float)Hs[(n * 32 + ((g >> 3) ^ n)) * 8 + (g & 7)];
                s_io[gi] = s1 + a2 + uvr[g2][r] * a3;
                float vx = (float)Xs[((0 * 16 + n) * 16 + ((g >> 3) ^ n)) * 8 + (g & 7)];
                float vy = (float)Xs[((1 * 16 + n) * 16 + ((g >> 3) ^ n)) * 8 + (g & 7)];
                float vz = (float)Xs[((2 * 16 + n) * 16 + ((g >> 3) ^ n)) * 8 + (g & 7)];
                v_io[gi * 3 + 0] = vx + accU[g2][0][r] * a1;
                v_io[gi * 3 + 1] = vy + accU[g2][1][r] * a1;
                v_io[gi * 3 + 2] = vz + accU[g2][2][r] * a1;
            }
        }
    }
}

// ---------------------------------------------------------------------------
extern "C" void kernel_launch(void* const* d_in, const int* in_sizes, int n_in,
                              void* d_out, int out_size, void* d_ws, size_t ws_size,
                              hipStream_t stream)
{
    const float* pos = (const float*)d_in[0];
    const float* emb = (const float*)d_in[1];
    const float* Wp1 = (const float*)d_in[2];
    const float* bp1 = (const float*)d_in[3];
    const float* Wp2 = (const float*)d_in[4];
    const float* bp2 = (const float*)d_in[5];
    const float* Ww  = (const float*)d_in[6];
    const float* bw  = (const float*)d_in[7];
    const float* Wu  = (const float*)d_in[8];
    const float* bu  = (const float*)d_in[9];
    const float* Wv  = (const float*)d_in[10];
    const float* bv  = (const float*)d_in[11];
    const float* Wu1 = (const float*)d_in[12];
    const float* bu1 = (const float*)d_in[13];
    const float* Wu2 = (const float*)d_in[14];
    const float* bu2 = (const float*)d_in[15];
    const int* z   = (const int*)d_in[16];
    const int* src = (const int*)d_in[17];
    const int* dst = (const int*)d_in[18];

    float* s_io = (float*)d_out;
    float* v_io = (float*)d_out + (size_t)NN * FF;

    char* ws = (char*)d_ws;
    unsigned int* phi_pk = (unsigned int*)ws;                 // NN*FF uints
    _Float16* xg    = (_Float16*)(phi_pk + (size_t)NN * FF);  // NN*3*FF
    _Float16* s_h   = xg + (size_t)NN * 3 * FF;               // NN*FF
    _Float16* Wuh   = s_h + (size_t)NN * FF;
    _Float16* Wvh   = Wuh  + 128 * 128;
    _Float16* Wu1h  = Wvh  + 128 * 128;
    _Float16* Wu2h  = Wu1h + 128 * 256;
    _Float16* Wp1h  = Wu2h + 384 * 128;
    _Float16* Wp2h  = Wp1h + 128 * 128;
    _Float16* Wwh32 = Wp2h + 384 * 128;                       // 256*32
    int* counts = (int*)(Wwh32 + 256 * 32);
    int* slots  = counts + NN;

    k_wconv <<<196, 256, 0, stream>>>(Wu, Wv, Wu1, Wu2, Wp1, Wp2, Ww, bw,
                                      Wuh, Wvh, Wu1h, Wu2h, Wp1h, Wp2h, Wwh32,
                                      counts);
    k_bucket<<<(EE + 255) / 256, 256, 0, stream>>>(dst, counts, slots);
    k_node_phi_mfma<<<(NN + 31) / 32, 256, 0, stream>>>(emb, z, Wp1h, bp1,
                                                        Wp2h, bp2,
                                                        phi_pk, s_h);
    k_edge_mfma<<<NN, 128, 0, stream>>>(pos, Wwh32, src, counts, slots,
                                        phi_pk, s_h, xg);
    k_update_mfma<<<(NN + 15) / 16, 256, 0, stream>>>(xg, s_h,
                                                      Wuh, Wvh, Wu1h, Wu2h,
                                                      bu, bv, bu1, bu2,
                                                      s_io, v_io);
}

// Round 8
// 379.330 us; speedup vs baseline: 1.0519x; 1.0074x over previous
//
#include <hip/hip_runtime.h>

#define NN 50000
#define EE 400000
#define FF 128
#define NRBF 20
#define MAXDEG 64
#define PI_OVER_CUT 0.6283185307179586f   // pi / 5.0

typedef _Float16 h8 __attribute__((ext_vector_type(8)));
typedef float    f4 __attribute__((ext_vector_type(4)));

union pk32 { unsigned int u; _Float16 h[2]; };

// ---------------------------------------------------------------------------
__global__ __launch_bounds__(256) void k_bucket(const int* __restrict__ dst,
                                                int* __restrict__ counts,
                                                int* __restrict__ slots) {
    int e = blockIdx.x * 256 + threadIdx.x;
    if (e < EE) {
        int n = dst[e];
        int slot = atomicAdd(&counts[n], 1);
        if (slot < MAXDEG) slots[n * MAXDEG + slot] = e;
    }
}

// Convert all GEMM weights to f16 once; also zeroes counts (merged k_zero).
__global__ __launch_bounds__(256) void k_wconv(
    const float* __restrict__ Wu, const float* __restrict__ Wv,
    const float* __restrict__ Wu1, const float* __restrict__ Wu2,
    const float* __restrict__ Wp1, const float* __restrict__ Wp2,
    const float* __restrict__ Ww, const float* __restrict__ bw,
    _Float16* __restrict__ Wuh, _Float16* __restrict__ Wvh,
    _Float16* __restrict__ Wu1h, _Float16* __restrict__ Wu2h,
    _Float16* __restrict__ Wp1h, _Float16* __restrict__ Wp2h,
    _Float16* __restrict__ Wwh32, int* __restrict__ counts)
{
    int i = blockIdx.x * 256 + threadIdx.x;
    if (i < NN) counts[i] = 0;
    if (i < 16384) { Wuh[i] = (_Float16)Wu[i]; Wvh[i] = (_Float16)Wv[i];
                     Wp1h[i] = (_Float16)Wp1[i]; }
    if (i < 32768) { Wu1h[i] = (_Float16)Wu1[i]; }
    if (i < 49152) { Wu2h[i] = (_Float16)Wu2[i]; Wp2h[i] = (_Float16)Wp2[i]; }
    if (i < 8192) {
        int col = i >> 5, k = i & 31;
        int sr = col < 128 ? col : col + 128;
        _Float16 v = (_Float16)0.f;
        if (k < 20)       v = (_Float16)Ww[sr * NRBF + k];
        else if (k == 20) v = (_Float16)bw[sr];
        Wwh32[i] = v;
    }
}

// ---------------------------------------------------------------------------
// K1 (MFMA): s0 = emb[z]; h1 = silu(Wp1 s + bp1); phi = Wp2 h1 + bp2.
// s0 carried forward as f16 (s_h).
__global__ __launch_bounds__(256) void k_node_phi_mfma(
    const float* __restrict__ emb, const int* __restrict__ z,
    const _Float16* __restrict__ Wp1h, const float* __restrict__ bp1,
    const _Float16* __restrict__ Wp2h, const float* __restrict__ bp2,
    unsigned int* __restrict__ phi_pk, _Float16* __restrict__ s_h)
{
    __shared__ _Float16 Ss[32 * 128];
    __shared__ _Float16 H1s[32 * 128];

    const int t    = threadIdx.x;
    const int lane = t & 63;
    const int w    = t >> 6;
    const int lr   = lane & 15;
    const int lq   = lane >> 4;
    const int n0   = blockIdx.x * 32;
    const f4 z4 = {0.f, 0.f, 0.f, 0.f};

    for (int i = t; i < 512; i += 256) {             // 32 rows x 16 granules
        int n = i >> 4, gr = i & 15;
        int nn = n0 + n; if (nn > NN - 1) nn = NN - 1;
        const float* sp = &emb[(size_t)z[nn] * FF + gr * 8];
        float4 aa = *(const float4*)sp;
        float4 bb = *(const float4*)(sp + 4);
        h8 hv;
        hv[0] = (_Float16)aa.x; hv[1] = (_Float16)aa.y;
        hv[2] = (_Float16)aa.z; hv[3] = (_Float16)aa.w;
        hv[4] = (_Float16)bb.x; hv[5] = (_Float16)bb.y;
        hv[6] = (_Float16)bb.z; hv[7] = (_Float16)bb.w;
        *(h8*)&Ss[(n * 16 + (gr ^ (n & 15))) * 8] = hv;
        *(h8*)&s_h[(size_t)nn * FF + gr * 8] = hv;
    }
    __syncthreads();

    f4 acc1[2][2];
    #pragma unroll
    for (int a = 0; a < 2; ++a)
        #pragma unroll
        for (int m = 0; m < 2; ++m) acc1[a][m] = z4;
    {
        const _Float16* bb = Wp1h + (size_t)lr * 128 + lq * 8;
        #pragma unroll
        for (int g2 = 0; g2 < 2; ++g2) {
            h8 bf[4];
            #pragma unroll
            for (int ks = 0; ks < 4; ++ks)
                bf[ks] = *(const h8*)(bb + ((2 * w + g2) * 16) * 128 + ks * 32);
            #pragma unroll
            for (int mt = 0; mt < 2; ++mt) {
                const int r = mt * 16 + lr;
                #pragma unroll
                for (int ks = 0; ks < 4; ++ks) {
                    h8 af = *(const h8*)&Ss[(r * 16 + ((ks * 4 + lq) ^ (r & 15))) * 8];
                    acc1[g2][mt] = __builtin_amdgcn_mfma_f32_16x16x32_f16(
                        af, bf[ks], acc1[g2][mt], 0, 0, 0);
                }
            }
        }
    }
    #pragma unroll
    for (int g2 = 0; g2 < 2; ++g2) {
        const int g = (2 * w + g2) * 16 + lr;
        const float b1 = bp1[g];
        #pragma unroll
        for (int mt = 0; mt < 2; ++mt)
            #pragma unroll
            for (int r = 0; r < 4; ++r) {
                float x = acc1[g2][mt][r] + b1;
                float y = x / (1.f + __expf(-x));
                int n = mt * 16 + lq * 4 + r;
                H1s[(n * 16 + ((g >> 3) ^ (n & 15))) * 8 + (g & 7)] = (_Float16)y;
            }
    }
    __syncthreads();

    f4 accS[2][2], accV[2][2];
    #pragma unroll
    for (int a = 0; a < 2; ++a)
        #pragma unroll
        for (int m = 0; m < 2; ++m) { accS[a][m] = z4; accV[a][m] = z4; }
    {
        const _Float16* bbs = Wp2h + (size_t)lr * 128 + lq * 8;
        const _Float16* bbv = Wp2h + (size_t)(256 + lr) * 128 + lq * 8;
        #pragma unroll
        for (int g2 = 0; g2 < 2; ++g2) {
            h8 bfs[4], bfv[4];
            #pragma unroll
            for (int ks = 0; ks < 4; ++ks) {
                bfs[ks] = *(const h8*)(bbs + ((2 * w + g2) * 16) * 128 + ks * 32);
                bfv[ks] = *(const h8*)(bbv + ((2 * w + g2) * 16) * 128 + ks * 32);
            }
            #pragma unroll
            for (int mt = 0; mt < 2; ++mt) {
                const int r = mt * 16 + lr;
                #pragma unroll
                for (int ks = 0; ks < 4; ++ks) {
                    h8 af = *(const h8*)&H1s[(r * 16 + ((ks * 4 + lq) ^ (r & 15))) * 8];
                    accS[g2][mt] = __builtin_amdgcn_mfma_f32_16x16x32_f16(
                        af, bfs[ks], accS[g2][mt], 0, 0, 0);
                    accV[g2][mt] = __builtin_amdgcn_mfma_f32_16x16x32_f16(
                        af, bfv[ks], accV[g2][mt], 0, 0, 0);
                }
            }
        }
    }
    #pragma unroll
    for (int g2 = 0; g2 < 2; ++g2) {
        const int g = (2 * w + g2) * 16 + lr;
        const float bsa = bp2[g], bva = bp2[256 + g];
        #pragma unroll
        for (int mt = 0; mt < 2; ++mt)
            #pragma unroll
            for (int r = 0; r < 4; ++r) {
                int n = mt * 16 + lq * 4 + r;
                int nn = n0 + n;
                if (nn < NN) {
                    pk32 pk;
                    pk.h[0] = (_Float16)(accS[g2][mt][r] + bsa);
                    pk.h[1] = (_Float16)(accV[g2][mt][r] + bva);
                    phi_pk[(size_t)nn * FF + g] = pk.u;
                }
            }
    }
}

// ---------------------------------------------------------------------------
// K2 (MFMA Wf): block-per-node, BARRIER-FREE. Wave w owns features
// [64w, 64w+64) and computes BOTH gates for them (4 s-tiles + 4 v-tiles of
// Wwh32 as B-fragments). All LDS (A-tile, dirs, wf) is wave-private, so all
// cross-lane exchange is within one wave -> no __syncthreads anywhere; the
// block's waves run fully decoupled and hide each other's latency.
__global__ __launch_bounds__(128) void k_edge_mfma(
    const float* __restrict__ pos,
    const _Float16* __restrict__ Wwh32,
    const int* __restrict__ src,
    const int* __restrict__ counts, const int* __restrict__ slots,
    const unsigned int* __restrict__ phi_pk,
    _Float16* __restrict__ s_h,
    _Float16* __restrict__ xg)
{
    __shared__ _Float16 A[2][16 * 32];        // per-wave swizzled rbf tile (2 KB)
    __shared__ float dirs[2][16][4];          // per-wave ux,uy,uz,asfloat(sI)
    __shared__ unsigned int wfi[2][16 * 66];  // per-wave packed {s,v} Wf (8.25 KB)

    const int t    = threadIdx.x;
    const int lane = t & 63;
    const int w    = t >> 6;     // wave id: features [64w, 64w+64)
    const int lr   = lane & 15;
    const int lq   = lane >> 4;
    const int m    = lane & 15;  // edge slot this lane serves
    const int ks   = lane >> 4;  // k-slot group (0..3)
    const int n    = blockIdx.x;
    const f4 z4 = {0.f, 0.f, 0.f, 0.f};

    // B-fragments: js<4 -> s-gate cols 64w+16js; js>=4 -> v-gate (L2-hot).
    h8 bf[8];
    #pragma unroll
    for (int js = 0; js < 8; ++js) {
        int col = (js < 4) ? (w * 64 + js * 16 + lr)
                           : (128 + w * 64 + (js - 4) * 16 + lr);
        bf[js] = *(const h8*)&Wwh32[(size_t)col * 32 + lq * 8];
    }

    const float px = pos[3 * n], py = pos[3 * n + 1], pz = pos[3 * n + 2];

    int deg = counts[n];
    deg = deg > MAXDEG ? MAXDEG : deg;

    const int gf = w * 64 + lane;            // this thread's feature
    const size_t gi = (size_t)n * FF + gf;
    float s_old = (float)s_h[gi];            // issued early, used at the end

    float acc_s = 0.f, av0 = 0.f, av1 = 0.f, av2 = 0.f;

    for (int t0 = 0; t0 < deg; t0 += 16) {
        const int degT = (deg - t0) < 16 ? (deg - t0) : 16;
        // ---- geometry + rbf: 4 lanes per edge (broadcast loads) ----
        {
            int mc = (m < degT) ? m : 0;     // clamp to a valid edge
            int e  = slots[n * MAXDEG + t0 + mc];
            int sI = src[e];
            float rx = px - pos[3 * sI];
            float ry = py - pos[3 * sI + 1];
            float rz = pz - pos[3 * sI + 2];
            float d = sqrtf(rx * rx + ry * ry + rz * rz);
            d = fmaxf(d, 1e-9f);
            float di = 1.f / d;
            if (lane < 16) {
                dirs[w][lane][0] = rx * di;
                dirs[w][lane][1] = ry * di;
                dirs[w][lane][2] = rz * di;
                dirs[w][lane][3] = __int_as_float(sI);
            }
            // lane covers k = ks + 4j, j=0..7 (k = ks..ks+28)
            float vv[8];
            #pragma unroll
            for (int j = 0; j < 5; ++j)      // k = ks+4j <= 19 for ks<4
                vv[j] = __sinf((float)(ks + 4 * j + 1) * PI_OVER_CUT * d) * di;
            vv[5] = (ks == 0) ? 1.0f : 0.f;  // k = 20: bias element
            vv[6] = 0.f; vv[7] = 0.f;
            #pragma unroll
            for (int j = 0; j < 8; ++j) {
                int k = ks + 4 * j;
                A[w][m * 32 + (((k >> 3) ^ (m & 3)) * 8) + (k & 7)] = (_Float16)vv[j];
            }
        }
        // ---- MFMA: both gates for this wave's 64 features; pack to dwords ----
        {
            h8 af = *(const h8*)&A[w][(lr * 4 + (lq ^ (lr & 3))) * 8];
            #pragma unroll
            for (int js = 0; js < 4; ++js) {
                f4 dd_s = __builtin_amdgcn_mfma_f32_16x16x32_f16(af, bf[js],     z4, 0, 0, 0);
                f4 dd_v = __builtin_amdgcn_mfma_f32_16x16x32_f16(af, bf[js + 4], z4, 0, 0, 0);
                #pragma unroll
                for (int r = 0; r < 4; ++r) {
                    pk32 pk;
                    pk.h[0] = (_Float16)dd_s[r];
                    pk.h[1] = (_Float16)dd_v[r];
                    wfi[w][(lq * 4 + r) * 66 + js * 16 + lr] = pk.u;
                }
            }
        }
        // ---- batched 16-wide phi gathers, then FMA pass ----
        {
            unsigned int phr[16];
            #pragma unroll
            for (int mm = 0; mm < 16; ++mm) {
                int sim = __builtin_amdgcn_readfirstlane(
                              __float_as_int(dirs[w][mm][3]));
                phr[mm] = (mm < degT) ? phi_pk[(size_t)sim * FF + gf] : 0u;
            }
            #pragma unroll
            for (int mm = 0; mm < 16; ++mm) {
                if (mm < degT) {
                    pk32 ph, wfu;
                    ph.u  = phr[mm];
                    wfu.u = wfi[w][mm * 66 + lane];
                    float ps = (float)ph.h[0] * (float)wfu.h[0];
                    float pv = (float)ph.h[1] * (float)wfu.h[1];
                    acc_s += ps;
                    av0 = fmaf(pv, dirs[w][mm][0], av0);
                    av1 = fmaf(pv, dirs[w][mm][1], av1);
                    av2 = fmaf(pv, dirs[w][mm][2], av2);
                }
            }
        }
    }

    s_h[gi] = (_Float16)(s_old + acc_s);
    xg[((size_t)n * 3 + 0) * FF + gf] = (_Float16)av0;
    xg[((size_t)n * 3 + 1) * FF + gf] = (_Float16)av1;
    xg[((size_t)n * 3 + 2) * FF + gf] = (_Float16)av2;
}

// ---------------------------------------------------------------------------
// K3: update block on f16 MFMA, 16 nodes/block (unchanged from round 7).
__global__ __launch_bounds__(256) void k_update_mfma(
    const _Float16* __restrict__ xg, const _Float16* __restrict__ s_h,
    const _Float16* __restrict__ Wuh, const _Float16* __restrict__ Wvh,
    const _Float16* __restrict__ Wu1h, const _Float16* __restrict__ Wu2h,
    const float* __restrict__ bu, const float* __restrict__ bv,
    const float* __restrict__ bu1, const float* __restrict__ bu2,
    float* __restrict__ s_io, float* __restrict__ v_io)
{
    __shared__ _Float16 Xs[48 * 128];    // A for GEMM1: row = c*16+n, k = f (12 KB)
    __shared__ _Float16 Hs[16 * 256];    // A for GEMM2: [s | Vn]          (8 KB)
    __shared__ _Float16 H1s[16 * 128];   // A for GEMM3                    (4 KB)

    const int t    = threadIdx.x;
    const int lane = t & 63;
    const int w    = t >> 6;     // wave 0..3
    const int lr   = lane & 15;  // A-row / B-col within tile
    const int lq   = lane >> 4;  // k-chunk selector
    const int n0   = blockIdx.x * 16;
    const f4 z4 = {0.f, 0.f, 0.f, 0.f};

    // ---- stage Xs from xg (48 rows x 16 granules) ----
    for (int i = t; i < 768; i += 256) {
        int row = i >> 4, gr = i & 15;
        int n = row & 15, c = row >> 4;
        int nn = n0 + n; if (nn > NN - 1) nn = NN - 1;
        uint4 d = *(const uint4*)&xg[((size_t)nn * 3 + c) * FF + gr * 8];
        *(uint4*)&Xs[(row * 16 + (gr ^ n)) * 8] = d;
    }
    // ---- stage s (f16 direct) -> Hs[:, 0:128) : 16 rows x 16 granules ----
    {
        int n = t >> 4, gr = t & 15;
        int nn = n0 + n; if (nn > NN - 1) nn = NN - 1;
        uint4 d = *(const uint4*)&s_h[(size_t)nn * FF + gr * 8];
        *(uint4*)&Hs[(n * 32 + (gr ^ n)) * 8] = d;
    }
    __syncthreads();

    // ---- GEMM1: U,V[c*16+n][g] ----
    f4 accU[2][3], accV[2][3];   // [g-subtile][c]
    #pragma unroll
    for (int a = 0; a < 2; ++a)
        #pragma unroll
        for (int c = 0; c < 3; ++c) { accU[a][c] = z4; accV[a][c] = z4; }

    {   // U pass
        const _Float16* bb = Wuh + (size_t)lr * 128 + lq * 8;
        h8 bfr[2][4];
        #pragma unroll
        for (int g2 = 0; g2 < 2; ++g2)
            #pragma unroll
            for (int ks = 0; ks < 4; ++ks)
                bfr[g2][ks] = *(const h8*)(bb + ((2 * w + g2) * 16) * 128 + ks * 32);
        #pragma unroll
        for (int c = 0; c < 3; ++c) {
            const int rr = c * 16 + lr;
            h8 af[4];
            #pragma unroll
            for (int ks = 0; ks < 4; ++ks)
                af[ks] = *(const h8*)&Xs[(rr * 16 + ((ks * 4 + lq) ^ lr)) * 8];
            #pragma unroll
            for (int g2 = 0; g2 < 2; ++g2)
                #pragma unroll
                for (int ks = 0; ks < 4; ++ks)
                    accU[g2][c] = __builtin_amdgcn_mfma_f32_16x16x32_f16(
                        af[ks], bfr[g2][ks], accU[g2][c], 0, 0, 0);
        }
    }
    {   // V pass
        const _Float16* bb = Wvh + (size_t)lr * 128 + lq * 8;
        h8 bfr[2][4];
        #pragma unroll
        for (int g2 = 0; g2 < 2; ++g2)
            #pragma unroll
            for (int ks = 0; ks < 4; ++ks)
                bfr[g2][ks] = *(const h8*)(bb + ((2 * w + g2) * 16) * 128 + ks * 32);
        #pragma unroll
        for (int c = 0; c < 3; ++c) {
            const int rr = c * 16 + lr;
            h8 af[4];
            #pragma unroll
            for (int ks = 0; ks < 4; ++ks)
                af[ks] = *(const h8*)&Xs[(rr * 16 + ((ks * 4 + lq) ^ lr)) * 8];
            #pragma unroll
            for (int g2 = 0; g2 < 2; ++g2)
                #pragma unroll
                for (int ks = 0; ks < 4; ++ks)
                    accV[g2][c] = __builtin_amdgcn_mfma_f32_16x16x32_f16(
                        af[ks], bfr[g2][ks], accV[g2][c], 0, 0, 0);
        }
    }

    // ---- epilogue 1: bias, u.v, Vn -> Hs[:,128:256) ----
    float uvr[2][4];
    #pragma unroll
    for (int g2 = 0; g2 < 2; ++g2) {
        const int g = (2 * w + g2) * 16 + lr;
        const float bU = bu[g], bV = bv[g];
        #pragma unroll
        for (int r = 0; r < 4; ++r) {
            float Ux = accU[g2][0][r] + bU;
            float Uy = accU[g2][1][r] + bU;
            float Uz = accU[g2][2][r] + bU;
            float Vx = accV[g2][0][r] + bV;
            float Vy = accV[g2][1][r] + bV;
            float Vz = accV[g2][2][r] + bV;
            accU[g2][0][r] = Ux;
            accU[g2][1][r] = Uy;
            accU[g2][2][r] = Uz;
            uvr[g2][r] = Ux * Vx + Uy * Vy + Uz * Vz;
            float vn = sqrtf(Vx * Vx + Vy * Vy + Vz * Vz);
            int n = lq * 4 + r;
            int gr = 16 + (g >> 3);
            Hs[(n * 32 + (gr ^ n)) * 8 + (g & 7)] = (_Float16)vn;
        }
    }
    __syncthreads();

    // ---- GEMM2: h1 = silu(Wu1 @ [s;Vn] + bu1) (single 16-row tile) ----
    f4 acc2[2];
    acc2[0] = z4; acc2[1] = z4;
    {
        const _Float16* bb = Wu1h + (size_t)lr * 256 + lq * 8;
        #pragma unroll
        for (int g2 = 0; g2 < 2; ++g2) {
            h8 bfr[8];
            #pragma unroll
            for (int ks = 0; ks < 8; ++ks)
                bfr[ks] = *(const h8*)(bb + ((2 * w + g2) * 16) * 256 + ks * 32);
            #pragma unroll
            for (int ks = 0; ks < 8; ++ks) {
                h8 af = *(const h8*)&Hs[(lr * 32 + ((ks * 4 + lq) ^ lr)) * 8];
                acc2[g2] = __builtin_amdgcn_mfma_f32_16x16x32_f16(
                    af, bfr[ks], acc2[g2], 0, 0, 0);
            }
        }
    }
    #pragma unroll
    for (int g2 = 0; g2 < 2; ++g2) {
        const int g = (2 * w + g2) * 16 + lr;
        const float b1 = bu1[g];
        #pragma unroll
        for (int r = 0; r < 4; ++r) {
            float x = acc2[g2][r] + b1;
            float y = x / (1.f + __expf(-x));
            int n = lq * 4 + r;
            H1s[(n * 16 + ((g >> 3) ^ n)) * 8 + (g & 7)] = (_Float16)y;
        }
    }
    __syncthreads();

    // ---- GEMM3: a = Wu2 @ h1 + bu2 (single 16-row tile) ----
    f4 acc3[3][2];
    #pragma unroll
    for (int a = 0; a < 3; ++a) { acc3[a][0] = z4; acc3[a][1] = z4; }
    {
        const _Float16* bb = Wu2h + (size_t)lr * 128 + lq * 8;
        #pragma unroll
        for (int ai = 0; ai < 3; ++ai)
            #pragma unroll
            for (int g2 = 0; g2 < 2; ++g2) {
                const int jt = ai * 8 + 2 * w + g2;
                h8 bfr[4];
                #pragma unroll
                for (int ks = 0; ks < 4; ++ks)
                    bfr[ks] = *(const h8*)(bb + (size_t)(jt * 16) * 128 + ks * 32);
                #pragma unroll
                for (int ks = 0; ks < 4; ++ks) {
                    h8 af = *(const h8*)&H1s[(lr * 16 + ((ks * 4 + lq) ^ lr)) * 8];
                    acc3[ai][g2] = __builtin_amdgcn_mfma_f32_16x16x32_f16(
                        af, bfr[ks], acc3[ai][g2], 0, 0, 0);
                }
            }
    }

    // ---- final epilogue: residuals from staged f16 LDS tiles ----
    #pragma unroll
    for (int g2 = 0; g2 < 2; ++g2) {
        const int g = (2 * w + g2) * 16 + lr;
        const float b1 = bu2[g], b2 = bu2[128 + g], b3 = bu2[256 + g];
        #pragma unroll
        for (int r = 0; r < 4; ++r) {
            int n = lq * 4 + r;
            int nn = n0 + n;
            if (nn < NN) {
                float a1 = acc3[0][g2][r] + b1;
                float a2 = acc3[1][g2][r] + b2;
                float a3 = acc3[2][g2][r] + b3;
                size_t gi = (size_t)nn * FF + g;
                float s1 = (float)Hs[(n * 32 + ((g >> 3) ^ n)) * 8 + (g & 7)];
                s_io[gi] = s1 + a2 + uvr[g2][r] * a3;
                float vx = (float)Xs[((0 * 16 + n) * 16 + ((g >> 3) ^ n)) * 8 + (g & 7)];
                float vy = (float)Xs[((1 * 16 + n) * 16 + ((g >> 3) ^ n)) * 8 + (g & 7)];
                float vz = (float)Xs[((2 * 16 + n) * 16 + ((g >> 3) ^ n)) * 8 + (g & 7)];
                v_io[gi * 3 + 0] = vx + accU[g2][0][r] * a1;
                v_io[gi * 3 + 1] = vy + accU[g2][1][r] * a1;
                v_io[gi * 3 + 2] = vz + accU[g2][2][r] * a1;
            }
        }
    }
}

// ---------------------------------------------------------------------------
extern "C" void kernel_launch(void* const* d_in, const int* in_sizes, int n_in,
                              void* d_out, int out_size, void* d_ws, size_t ws_size,
                              hipStream_t stream)
{
    const float* pos = (const float*)d_in[0];
    const float* emb = (const float*)d_in[1];
    const float* Wp1 = (const float*)d_in[2];
    const float* bp1 = (const float*)d_in[3];
    const float* Wp2 = (const float*)d_in[4];
    const float* bp2 = (const float*)d_in[5];
    const float* Ww  = (const float*)d_in[6];
    const float* bw  = (const float*)d_in[7];
    const float* Wu  = (const float*)d_in[8];
    const float* bu  = (const float*)d_in[9];
    const float* Wv  = (const float*)d_in[10];
    const float* bv  = (const float*)d_in[11];
    const float* Wu1 = (const float*)d_in[12];
    const float* bu1 = (const float*)d_in[13];
    const float* Wu2 = (const float*)d_in[14];
    const float* bu2 = (const float*)d_in[15];
    const int* z   = (const int*)d_in[16];
    const int* src = (const int*)d_in[17];
    const int* dst = (const int*)d_in[18];

    float* s_io = (float*)d_out;
    float* v_io = (float*)d_out + (size_t)NN * FF;

    char* ws = (char*)d_ws;
    unsigned int* phi_pk = (unsigned int*)ws;                 // NN*FF uints
    _Float16* xg    = (_Float16*)(phi_pk + (size_t)NN * FF);  // NN*3*FF
    _Float16* s_h   = xg + (size_t)NN * 3 * FF;               // NN*FF
    _Float16* Wuh   = s_h + (size_t)NN * FF;
    _Float16* Wvh   = Wuh  + 128 * 128;
    _Float16* Wu1h  = Wvh  + 128 * 128;
    _Float16* Wu2h  = Wu1h + 128 * 256;
    _Float16* Wp1h  = Wu2h + 384 * 128;
    _Float16* Wp2h  = Wp1h + 128 * 128;
    _Float16* Wwh32 = Wp2h + 384 * 128;                       // 256*32
    int* counts = (int*)(Wwh32 + 256 * 32);
    int* slots  = counts + NN;

    k_wconv <<<196, 256, 0, stream>>>(Wu, Wv, Wu1, Wu2, Wp1, Wp2, Ww, bw,
                                      Wuh, Wvh, Wu1h, Wu2h, Wp1h, Wp2h, Wwh32,
                                      counts);
    k_bucket<<<(EE + 255) / 256, 256, 0, stream>>>(dst, counts, slots);
    k_node_phi_mfma<<<(NN + 31) / 32, 256, 0, stream>>>(emb, z, Wp1h, bp1,
                                                        Wp2h, bp2,
                                                        phi_pk, s_h);
    k_edge_mfma<<<NN, 128, 0, stream>>>(pos, Wwh32, src, counts, slots,
                                        phi_pk, s_h, xg);
    k_update_mfma<<<(NN + 15) / 16, 256, 0, stream>>>(xg, s_h,
                                                      Wuh, Wvh, Wu1h, Wu2h,
                                                      bu, bv, bu1, bu2,
                                                      s_io, v_io);
}